// Round 2
// baseline (3205.972 us; speedup 1.0000x reference)
//
#include <hip/hip_runtime.h>
#include <cstddef>
#include <cstdint>

#define BB 8
#define MD 256
#define NP 4096
#define HH 8
#define FF 16
#define SS 32
#define S3 32768
#define CC 152      // H*(F+3)
#define KC 24       // H*3
#define PTS (BB*HH*NP)   // 262144
#define BPT (HH*NP)      // points per batch = 32768
#define BN_CNT (BB*NP)   // 32768
#define EPSV 1e-5f

// ---------------- GEMM: kv[b,o,n] = sum_m W[o,m] * x[b,m,n] ----------------
__global__ __launch_bounds__(256) void k_gemm(const float* __restrict__ x,
                                              const float* __restrict__ W,
                                              float* __restrict__ kv) {
    int oc0 = blockIdx.x * 8;           // 19 blocks * 8 = 152 channels
    int nt  = blockIdx.y;               // 16 n-tiles
    int b   = blockIdx.z;
    int tid = threadIdx.x;
    int n = nt * 256 + tid;

    float acc[8] = {0.f,0.f,0.f,0.f,0.f,0.f,0.f,0.f};
    const float* xb = x + (size_t)b * MD * NP + n;
    const float* Wb = W + (size_t)oc0 * MD;
#pragma unroll 4
    for (int m = 0; m < MD; ++m) {
        float xv = xb[(size_t)m * NP];
#pragma unroll
        for (int r = 0; r < 8; ++r)
            acc[r] = fmaf(Wb[r * MD + m], xv, acc[r]);   // W uniform -> s_load
    }
#pragma unroll
    for (int r = 0; r < 8; ++r)
        kv[((size_t)b * CC + oc0 + r) * NP + n] = acc[r];
}

// ------------- BN stats over (B,N) for all 152 kv channels -----------------
__global__ __launch_bounds__(256) void k_stats_kv(const float* __restrict__ kv,
                                                  const float* __restrict__ kg,
                                                  const float* __restrict__ kb,
                                                  const float* __restrict__ vg,
                                                  const float* __restrict__ vb,
                                                  float* __restrict__ A,
                                                  float* __restrict__ Bv) {
    int o = blockIdx.x, tid = threadIdx.x;
    float s = 0.f, ss = 0.f;
    for (int b = 0; b < BB; ++b) {
        const float* p = kv + ((size_t)b * CC + o) * NP;
        for (int n = tid; n < NP; n += 256) { float v = p[n]; s += v; ss = fmaf(v, v, ss); }
    }
#pragma unroll
    for (int off = 32; off > 0; off >>= 1) { s += __shfl_down(s, off); ss += __shfl_down(ss, off); }
    __shared__ float sh[8];
    int lane = tid & 63, w = tid >> 6;
    if (lane == 0) { sh[w] = s; sh[4 + w] = ss; }
    __syncthreads();
    if (tid == 0) {
        float S_ = sh[0] + sh[1] + sh[2] + sh[3];
        float SSv = sh[4] + sh[5] + sh[6] + sh[7];
        float mean = S_ * (1.f / BN_CNT);
        float var  = SSv * (1.f / BN_CNT) - mean * mean;
        float rstd = rsqrtf(var + EPSV);
        float g  = (o < KC) ? kg[o] : vg[o - KC];
        float be = (o < KC) ? kb[o] : vb[o - KC];
        A[o]  = rstd * g;
        Bv[o] = be - mean * rstd * g;
    }
}

// ------- per-point: BN keys -> affine -> tanh -> lattice idx + frac --------
__global__ __launch_bounds__(256) void k_prep(const float* __restrict__ kv,
                                              const float* __restrict__ pcd,
                                              const float* __restrict__ A,
                                              const float* __restrict__ Bv,
                                              const float* __restrict__ R,
                                              const float* __restrict__ t,
                                              int* __restrict__ base,
                                              float* __restrict__ frac) {
    int gid = blockIdx.x * 256 + threadIdx.x;
    int b = gid >> 15, h = (gid >> 12) & 7, n = gid & 4095;

    float p[3];
#pragma unroll
    for (int i = 0; i < 3; ++i) {
        int c = h * 3 + i;
        float v = kv[((size_t)b * CC + c) * NP + n];
        p[i] = pcd[((size_t)b * 3 + i) * NP + n] + fmaf(A[c], v, Bv[c]);
    }
    int fl[3]; float fr[3];
#pragma unroll
    for (int i = 0; i < 3; ++i) {
        float key = R[h * 9 + i * 3 + 0] * p[0] + R[h * 9 + i * 3 + 1] * p[1] +
                    R[h * 9 + i * 3 + 2] * p[2] + t[h * 3 + i];
        float lat = tanhf(key);
        float pos = (lat + 1.f) * 0.5f * (SS - 1);
        float flf = fminf(fmaxf(floorf(pos), 0.f), (float)(SS - 2));
        fr[i] = pos - flf;
        fl[i] = (int)flf;
    }
    base[gid] = (fl[0] * SS + fl[1]) * SS + fl[2];
    frac[gid]           = fr[0];
    frac[PTS + gid]     = fr[1];
    frac[2 * PTS + gid] = fr[2];
}

// ------- splat (one batch): scatter-add values * w8 onto lattice z_b -------
__global__ __launch_bounds__(256) void k_splat(const float* __restrict__ kv,
                                               const float* __restrict__ A,
                                               const float* __restrict__ Bv,
                                               const int* __restrict__ base,
                                               const float* __restrict__ frac,
                                               float* __restrict__ zb_all, int b) {
    int lid = blockIdx.x * 256 + threadIdx.x;   // 0 .. BPT-1
    int h = lid >> 12, n = lid & 4095;
    int gid = b * BPT + lid;

    float vals[FF];
#pragma unroll
    for (int f = 0; f < FF; ++f) {
        int c = KC + h * FF + f;
        vals[f] = fmaf(A[c], kv[((size_t)b * CC + c) * NP + n], Bv[c]);
    }
    int bs = base[gid];
    float fx = frac[gid], fy = frac[PTS + gid], fz = frac[2 * PTS + gid];
    float wx[2] = {1.f - fx, fx}, wy[2] = {1.f - fy, fy}, wz[2] = {1.f - fz, fz};
    float* zb = zb_all + (size_t)h * FF * S3;
#pragma unroll
    for (int dx = 0; dx < 2; ++dx)
#pragma unroll
    for (int dy = 0; dy < 2; ++dy)
#pragma unroll
    for (int dz = 0; dz < 2; ++dz) {
        int idx = bs + dx * (SS * SS) + dy * SS + dz;
        float w = wx[dx] * wy[dy] * wz[dz];
#pragma unroll
        for (int f = 0; f < FF; ++f)
            atomicAdd(&zb[(size_t)f * S3 + idx], vals[f] * w);
    }
}

// ---- grouped 3x3x3 conv over one batch's lattice (SAME, zero pad) ---------
__global__ __launch_bounds__(256) void k_conv(const float* __restrict__ z,
                                              const float* __restrict__ cw,
                                              const float* __restrict__ cb,
                                              float* __restrict__ zc) {
    __shared__ float z_l[4][3][34][34];   // fi-chunk, x-1..x+1, y pad, z pad
    __shared__ float w_l[16 * 108];       // [fo][ci*27+d]
    int xs = blockIdx.x;      // 0..31
    int h  = blockIdx.y;
    int tid = threadIdx.x;
    int zp = tid & 31;
    int y0 = (tid >> 5) * 4;

    float acc[16][4];
#pragma unroll
    for (int fo = 0; fo < 16; ++fo)
#pragma unroll
        for (int cy = 0; cy < 4; ++cy) acc[fo][cy] = 0.f;

    for (int chunk = 0; chunk < 4; ++chunk) {
        __syncthreads();
        // stage z slab (with zero halo)
        for (int ci = 0; ci < 4; ++ci) {
            int fi = chunk * 4 + ci;
            const float* zsrc = z + ((size_t)h * FF + fi) * S3;
            for (int dxi = 0; dxi < 3; ++dxi) {
                int gx = xs + dxi - 1;
                bool xok = (gx >= 0) && (gx < SS);
                for (int i = tid; i < 34 * 34; i += 256) {
                    int yi = i / 34, zi = i % 34;
                    int gy = yi - 1, gz = zi - 1;
                    float v = 0.f;
                    if (xok && gy >= 0 && gy < SS && gz >= 0 && gz < SS)
                        v = zsrc[(gx * SS + gy) * SS + gz];
                    z_l[ci][dxi][yi][zi] = v;
                }
            }
        }
        // stage weights for this fi-chunk
        for (int i = tid; i < 16 * 108; i += 256)
            w_l[i] = cw[(size_t)(h * 16 + i / 108) * 432 + chunk * 108 + (i % 108)];
        __syncthreads();

#pragma unroll 1
        for (int ci = 0; ci < 4; ++ci) {
#pragma unroll 1
            for (int dx = 0; dx < 3; ++dx) {
#pragma unroll 1
                for (int dy = 0; dy < 3; ++dy) {
#pragma unroll
                    for (int dz = 0; dz < 3; ++dz) {
                        float zv[4];
#pragma unroll
                        for (int cy = 0; cy < 4; ++cy)
                            zv[cy] = z_l[ci][dx][y0 + cy + dy][zp + dz];
                        int wbase = ci * 27 + dx * 9 + dy * 3 + dz;
#pragma unroll
                        for (int fo = 0; fo < 16; ++fo) {
                            float wv = w_l[fo * 108 + wbase];
#pragma unroll
                            for (int cy = 0; cy < 4; ++cy)
                                acc[fo][cy] = fmaf(wv, zv[cy], acc[fo][cy]);
                        }
                    }
                }
            }
        }
    }
#pragma unroll
    for (int fo = 0; fo < 16; ++fo) {
        float bias = cb[h * 16 + fo];
#pragma unroll
        for (int cy = 0; cy < 4; ++cy)
            zc[((size_t)h * FF + fo) * S3 + (xs * SS + y0 + cy) * SS + zp] =
                acc[fo][cy] + bias;
    }
}

// ------ slice (one batch): gather back with same trilinear weights ---------
__global__ __launch_bounds__(256) void k_slice(const int* __restrict__ base,
                                               const float* __restrict__ frac,
                                               const float* __restrict__ zc,
                                               float* __restrict__ out, int b) {
    int lid = blockIdx.x * 256 + threadIdx.x;
    int h = lid >> 12, n = lid & 4095;
    int gid = b * BPT + lid;
    int bs = base[gid];
    float fx = frac[gid], fy = frac[PTS + gid], fz = frac[2 * PTS + gid];
    float wx[2] = {1.f - fx, fx}, wy[2] = {1.f - fy, fy}, wz[2] = {1.f - fz, fz};
    const float* zb = zc + (size_t)h * FF * S3;

    float acc[FF];
#pragma unroll
    for (int f = 0; f < FF; ++f) acc[f] = 0.f;
#pragma unroll
    for (int dx = 0; dx < 2; ++dx)
#pragma unroll
    for (int dy = 0; dy < 2; ++dy)
#pragma unroll
    for (int dz = 0; dz < 2; ++dz) {
        int idx = bs + dx * (SS * SS) + dy * SS + dz;
        float w = wx[dx] * wy[dy] * wz[dz];
#pragma unroll
        for (int f = 0; f < FF; ++f)
            acc[f] = fmaf(zb[(size_t)f * S3 + idx], w, acc[f]);
    }
#pragma unroll
    for (int f = 0; f < FF; ++f)
        out[((size_t)b * (HH * FF) + h * FF + f) * NP + n] = acc[f];
}

// ------------- BN stats over (B,N) for the 128 sliced channels -------------
__global__ __launch_bounds__(256) void k_stats2(const float* __restrict__ out,
                                                const float* __restrict__ ag,
                                                const float* __restrict__ ab,
                                                float* __restrict__ A2,
                                                float* __restrict__ B2) {
    int c = blockIdx.x, tid = threadIdx.x;
    float s = 0.f, ss = 0.f;
    for (int b = 0; b < BB; ++b) {
        const float* p = out + ((size_t)b * (HH * FF) + c) * NP;
        for (int n = tid; n < NP; n += 256) { float v = p[n]; s += v; ss = fmaf(v, v, ss); }
    }
#pragma unroll
    for (int off = 32; off > 0; off >>= 1) { s += __shfl_down(s, off); ss += __shfl_down(ss, off); }
    __shared__ float sh[8];
    int lane = tid & 63, w = tid >> 6;
    if (lane == 0) { sh[w] = s; sh[4 + w] = ss; }
    __syncthreads();
    if (tid == 0) {
        float S_ = sh[0] + sh[1] + sh[2] + sh[3];
        float SSv = sh[4] + sh[5] + sh[6] + sh[7];
        float mean = S_ * (1.f / BN_CNT);
        float var  = SSv * (1.f / BN_CNT) - mean * mean;
        float rstd = rsqrtf(var + EPSV);
        A2[c] = rstd * ag[c];
        B2[c] = ab[c] - mean * rstd * ag[c];
    }
}

// ---------------- final BN + ReLU in-place on d_out ------------------------
__global__ __launch_bounds__(256) void k_bnrelu(float* __restrict__ out,
                                                const float* __restrict__ A2,
                                                const float* __restrict__ B2) {
    int gid = blockIdx.x * 256 + threadIdx.x;
    int c = (gid >> 12) & 127;
    float v = out[gid];
    out[gid] = fmaxf(fmaf(A2[c], v, B2[c]), 0.f);
}

// ---------------------------------------------------------------------------
extern "C" void kernel_launch(void* const* d_in, const int* in_sizes, int n_in,
                              void* d_out, int out_size, void* d_ws, size_t ws_size,
                              hipStream_t stream) {
    (void)in_sizes; (void)n_in; (void)out_size; (void)ws_size;
    const float* x   = (const float*)d_in[0];
    const float* pcd = (const float*)d_in[1];
    const float* W   = (const float*)d_in[2];
    const float* kg  = (const float*)d_in[3];
    const float* kb  = (const float*)d_in[4];
    const float* vg  = (const float*)d_in[5];
    const float* vb  = (const float*)d_in[6];
    const float* R   = (const float*)d_in[7];
    const float* t   = (const float*)d_in[8];
    const float* cw  = (const float*)d_in[9];
    const float* cb  = (const float*)d_in[10];
    const float* ag  = (const float*)d_in[11];
    const float* ab  = (const float*)d_in[12];
    float* out = (float*)d_out;
    char* ws = (char*)d_ws;

    // workspace layout (bytes), total 57,675,776 (~55 MB)
    float* kv   = (float*)(ws + 0);            // 19,922,944
    int*   base = (int*)  (ws + 19922944ULL);  //  1,048,576
    float* frac = (float*)(ws + 20971520ULL);  //  3,145,728
    float* A    = (float*)(ws + 24117248ULL);  //  1,024
    float* Bv   = (float*)(ws + 24118272ULL);  //  1,024
    float* A2   = (float*)(ws + 24119296ULL);  //  1,024
    float* B2   = (float*)(ws + 24120320ULL);  //  1,024
    float* z_b  = (float*)(ws + 24121344ULL);  // 16,777,216 (one batch)
    float* zc_b = (float*)(ws + 40898560ULL);  // 16,777,216 (one batch)

    k_gemm<<<dim3(19, 16, BB), 256, 0, stream>>>(x, W, kv);
    k_stats_kv<<<dim3(CC), 256, 0, stream>>>(kv, kg, kb, vg, vb, A, Bv);
    k_prep<<<dim3(PTS / 256), 256, 0, stream>>>(kv, pcd, A, Bv, R, t, base, frac);

    for (int b = 0; b < BB; ++b) {
        hipMemsetAsync(z_b, 0, (size_t)16777216, stream);
        k_splat<<<dim3(BPT / 256), 256, 0, stream>>>(kv, A, Bv, base, frac, z_b, b);
        k_conv<<<dim3(SS, HH), 256, 0, stream>>>(z_b, cw, cb, zc_b);
        k_slice<<<dim3(BPT / 256), 256, 0, stream>>>(base, frac, zc_b, out, b);
    }

    k_stats2<<<dim3(HH * FF), 256, 0, stream>>>(out, ag, ab, A2, B2);
    k_bnrelu<<<dim3((BB * HH * FF * NP) / 256), 256, 0, stream>>>(out, A2, B2);
}

// Round 3
// 2871.104 us; speedup vs baseline: 1.1166x; 1.1166x over previous
//
#include <hip/hip_runtime.h>
#include <cstddef>
#include <cstdint>

#define BB 8
#define MD 256
#define NP 4096
#define HH 8
#define FF 16
#define SS 32
#define S3 32768
#define CC 152      // H*(F+3)
#define KC 24       // H*3
#define PTS (BB*HH*NP)   // 262144
#define BPT (HH*NP)      // points per batch = 32768
#define BN_CNT (BB*NP)   // 32768
#define EPSV 1e-5f

// -------- GEMM: kv[b,o,n] = sum_m W[o,m] * x[b,m,n]; 16 oc per block -------
__global__ __launch_bounds__(256) void k_gemm(const float* __restrict__ x,
                                              const float* __restrict__ W,
                                              float* __restrict__ kv) {
    int oc0 = blockIdx.x * 16;          // 10 blocks * 16 = 160 (guard >=152)
    int nt  = blockIdx.y;               // 16 n-tiles
    int b   = blockIdx.z;
    int tid = threadIdx.x;
    int n = nt * 256 + tid;

    float acc[16];
#pragma unroll
    for (int r = 0; r < 16; ++r) acc[r] = 0.f;
    const float* xb = x + (size_t)b * MD * NP + n;
#pragma unroll 4
    for (int m = 0; m < MD; ++m) {
        float xv = xb[(size_t)m * NP];
#pragma unroll
        for (int r = 0; r < 16; ++r) {
            int rr = (oc0 + r < CC) ? (oc0 + r) : (CC - 1);   // clamp W row (uniform)
            acc[r] = fmaf(W[(size_t)rr * MD + m], xv, acc[r]);
        }
    }
#pragma unroll
    for (int r = 0; r < 16; ++r)
        if (oc0 + r < CC)
            kv[((size_t)b * CC + oc0 + r) * NP + n] = acc[r];
}

// ------------- BN stats over (B,N) for all 152 kv channels -----------------
__global__ __launch_bounds__(256) void k_stats_kv(const float* __restrict__ kv,
                                                  const float* __restrict__ kg,
                                                  const float* __restrict__ kb,
                                                  const float* __restrict__ vg,
                                                  const float* __restrict__ vb,
                                                  float* __restrict__ A,
                                                  float* __restrict__ Bv) {
    int o = blockIdx.x, tid = threadIdx.x;
    float s = 0.f, ss = 0.f;
    for (int b = 0; b < BB; ++b) {
        const float* p = kv + ((size_t)b * CC + o) * NP;
        for (int n = tid; n < NP; n += 256) { float v = p[n]; s += v; ss = fmaf(v, v, ss); }
    }
#pragma unroll
    for (int off = 32; off > 0; off >>= 1) { s += __shfl_down(s, off); ss += __shfl_down(ss, off); }
    __shared__ float sh[8];
    int lane = tid & 63, w = tid >> 6;
    if (lane == 0) { sh[w] = s; sh[4 + w] = ss; }
    __syncthreads();
    if (tid == 0) {
        float S_ = sh[0] + sh[1] + sh[2] + sh[3];
        float SSv = sh[4] + sh[5] + sh[6] + sh[7];
        float mean = S_ * (1.f / BN_CNT);
        float var  = SSv * (1.f / BN_CNT) - mean * mean;
        float rstd = rsqrtf(var + EPSV);
        float g  = (o < KC) ? kg[o] : vg[o - KC];
        float be = (o < KC) ? kb[o] : vb[o - KC];
        A[o]  = rstd * g;
        Bv[o] = be - mean * rstd * g;
    }
}

// ------- per-point: BN keys -> affine -> tanh -> lattice idx + frac --------
__global__ __launch_bounds__(256) void k_prep(const float* __restrict__ kv,
                                              const float* __restrict__ pcd,
                                              const float* __restrict__ A,
                                              const float* __restrict__ Bv,
                                              const float* __restrict__ R,
                                              const float* __restrict__ t,
                                              int* __restrict__ base,
                                              float* __restrict__ frac) {
    int gid = blockIdx.x * 256 + threadIdx.x;
    int b = gid >> 15, h = (gid >> 12) & 7, n = gid & 4095;

    float p[3];
#pragma unroll
    for (int i = 0; i < 3; ++i) {
        int c = h * 3 + i;
        float v = kv[((size_t)b * CC + c) * NP + n];
        p[i] = pcd[((size_t)b * 3 + i) * NP + n] + fmaf(A[c], v, Bv[c]);
    }
    int fl[3]; float fr[3];
#pragma unroll
    for (int i = 0; i < 3; ++i) {
        float key = R[h * 9 + i * 3 + 0] * p[0] + R[h * 9 + i * 3 + 1] * p[1] +
                    R[h * 9 + i * 3 + 2] * p[2] + t[h * 3 + i];
        float lat = tanhf(key);
        float pos = (lat + 1.f) * 0.5f * (SS - 1);
        float flf = fminf(fmaxf(floorf(pos), 0.f), (float)(SS - 2));
        fr[i] = pos - flf;
        fl[i] = (int)flf;
    }
    base[gid] = (fl[0] * SS + fl[1]) * SS + fl[2];
    frac[gid]           = fr[0];
    frac[PTS + gid]     = fr[1];
    frac[2 * PTS + gid] = fr[2];
}

// --- splat (one batch): thread per (point, corner); z layout [h][cell][16] --
__global__ __launch_bounds__(256) void k_splat(const float* __restrict__ kv,
                                               const float* __restrict__ A,
                                               const float* __restrict__ Bv,
                                               const int* __restrict__ base,
                                               const float* __restrict__ frac,
                                               float* __restrict__ z, int b) {
    int lid = blockIdx.x * 256 + threadIdx.x;   // 0 .. BPT-1
    int cor = blockIdx.y;                       // corner 0..7
    int h = lid >> 12, n = lid & 4095;
    int gid = b * BPT + lid;

    int dxb = (cor >> 2) & 1, dyb = (cor >> 1) & 1, dzb = cor & 1;
    float fx = frac[gid], fy = frac[PTS + gid], fz = frac[2 * PTS + gid];
    float w = (dxb ? fx : 1.f - fx) * (dyb ? fy : 1.f - fy) * (dzb ? fz : 1.f - fz);
    int cell = base[gid] + dxb * (SS * SS) + dyb * SS + dzb;

    float* dst = z + ((size_t)h * S3 + cell) * FF;
#pragma unroll
    for (int f = 0; f < FF; ++f) {
        int c = KC + h * FF + f;
        float val = fmaf(A[c], kv[((size_t)b * CC + c) * NP + n], Bv[c]);
        atomicAdd(&dst[f], val * w);
    }
}

// ---- grouped 3x3x3 conv, one batch; z/zc layout [h][cell][16] -------------
__global__ __launch_bounds__(256) void k_conv(const float* __restrict__ z,
                                              const float* __restrict__ cw,
                                              const float* __restrict__ cb,
                                              float* __restrict__ zc) {
    __shared__ float z_l[4][3][18][34];   // [ci][x-1..x+1][y half + halo][z pad]
    __shared__ float w_l[16 * 108];       // [fo][ci*27 + d]
    int xs = blockIdx.x;      // 0..31
    int yh = blockIdx.y;      // 0..1
    int h  = blockIdx.z;
    int tid = threadIdx.x;
    int zp = tid & 31;
    int yl = tid >> 5;        // 0..7 -> owns y = yh*16 + yl*2 + {0,1}

    float acc[16][2];
#pragma unroll
    for (int fo = 0; fo < 16; ++fo) { acc[fo][0] = 0.f; acc[fo][1] = 0.f; }

    for (int chunk = 0; chunk < 4; ++chunk) {
        int ci0 = chunk * 4;
        __syncthreads();
        // stage z slab as float4 (4 input channels), with zero halo
        for (int i = tid; i < 3 * 18 * 34; i += 256) {
            int dxi = i / 612, rem = i % 612;
            int yy = rem / 34, zi = rem % 34;
            int gx = xs + dxi - 1, gy = yh * 16 + yy - 1, gz = zi - 1;
            float4 v = make_float4(0.f, 0.f, 0.f, 0.f);
            if (gx >= 0 && gx < SS && gy >= 0 && gy < SS && gz >= 0 && gz < SS)
                v = *reinterpret_cast<const float4*>(
                        &z[((size_t)h * S3 + (gx * 1024 + gy * 32 + gz)) * FF + ci0]);
            z_l[0][dxi][yy][zi] = v.x;
            z_l[1][dxi][yy][zi] = v.y;
            z_l[2][dxi][yy][zi] = v.z;
            z_l[3][dxi][yy][zi] = v.w;
        }
        // stage weights for this ci-chunk: w_l[fo*108 + lci*27 + d]
        for (int i = tid; i < 16 * 108; i += 256)
            w_l[i] = cw[((size_t)(h * 16 + i / 108) * 16 + ci0) * 27 + (i % 108)];
        __syncthreads();

#pragma unroll 1
        for (int ci = 0; ci < 4; ++ci) {
#pragma unroll 1
            for (int dx = 0; dx < 3; ++dx) {
#pragma unroll
                for (int dy = 0; dy < 3; ++dy) {
#pragma unroll
                    for (int dz = 0; dz < 3; ++dz) {
                        float zv0 = z_l[ci][dx][yl * 2 + 0 + dy][zp + dz];
                        float zv1 = z_l[ci][dx][yl * 2 + 1 + dy][zp + dz];
                        int wbase = ci * 27 + dx * 9 + dy * 3 + dz;
#pragma unroll
                        for (int fo = 0; fo < 16; ++fo) {
                            float wv = w_l[fo * 108 + wbase];
                            acc[fo][0] = fmaf(wv, zv0, acc[fo][0]);
                            acc[fo][1] = fmaf(wv, zv1, acc[fo][1]);
                        }
                    }
                }
            }
        }
    }
#pragma unroll
    for (int cy = 0; cy < 2; ++cy) {
        int cell = xs * 1024 + (yh * 16 + yl * 2 + cy) * 32 + zp;
        float* dst = zc + ((size_t)h * S3 + cell) * FF;
#pragma unroll
        for (int q = 0; q < 4; ++q) {
            float4 v;
            v.x = acc[q * 4 + 0][cy] + cb[h * 16 + q * 4 + 0];
            v.y = acc[q * 4 + 1][cy] + cb[h * 16 + q * 4 + 1];
            v.z = acc[q * 4 + 2][cy] + cb[h * 16 + q * 4 + 2];
            v.w = acc[q * 4 + 3][cy] + cb[h * 16 + q * 4 + 3];
            *reinterpret_cast<float4*>(&dst[q * 4]) = v;
        }
    }
}

// --- slice (one batch): thread per (point, fo-quad); zc [h][cell][16] ------
__global__ __launch_bounds__(256) void k_slice(const int* __restrict__ base,
                                               const float* __restrict__ frac,
                                               const float* __restrict__ zc,
                                               float* __restrict__ out, int b) {
    int lid = blockIdx.x * 256 + threadIdx.x;   // 0..BPT-1
    int foq = blockIdx.y;                       // 0..3
    int h = lid >> 12, n = lid & 4095;
    int gid = b * BPT + lid;
    int bs = base[gid];
    float fx = frac[gid], fy = frac[PTS + gid], fz = frac[2 * PTS + gid];
    float wx[2] = {1.f - fx, fx}, wy[2] = {1.f - fy, fy}, wz[2] = {1.f - fz, fz};
    const float* zb = zc + (size_t)h * S3 * FF + foq * 4;

    float a0 = 0.f, a1 = 0.f, a2 = 0.f, a3 = 0.f;
#pragma unroll
    for (int dx = 0; dx < 2; ++dx)
#pragma unroll
    for (int dy = 0; dy < 2; ++dy)
#pragma unroll
    for (int dz = 0; dz < 2; ++dz) {
        int cell = bs + dx * (SS * SS) + dy * SS + dz;
        float w = wx[dx] * wy[dy] * wz[dz];
        float4 v = *reinterpret_cast<const float4*>(&zb[(size_t)cell * FF]);
        a0 = fmaf(v.x, w, a0); a1 = fmaf(v.y, w, a1);
        a2 = fmaf(v.z, w, a2); a3 = fmaf(v.w, w, a3);
    }
    size_t ob = ((size_t)b * (HH * FF) + h * FF + foq * 4) * NP + n;
    out[ob]          = a0;
    out[ob + NP]     = a1;
    out[ob + 2 * NP] = a2;
    out[ob + 3 * NP] = a3;
}

// ------------- BN stats over (B,N) for the 128 sliced channels -------------
__global__ __launch_bounds__(256) void k_stats2(const float* __restrict__ out,
                                                const float* __restrict__ ag,
                                                const float* __restrict__ ab,
                                                float* __restrict__ A2,
                                                float* __restrict__ B2) {
    int c = blockIdx.x, tid = threadIdx.x;
    float s = 0.f, ss = 0.f;
    for (int b = 0; b < BB; ++b) {
        const float* p = out + ((size_t)b * (HH * FF) + c) * NP;
        for (int n = tid; n < NP; n += 256) { float v = p[n]; s += v; ss = fmaf(v, v, ss); }
    }
#pragma unroll
    for (int off = 32; off > 0; off >>= 1) { s += __shfl_down(s, off); ss += __shfl_down(ss, off); }
    __shared__ float sh[8];
    int lane = tid & 63, w = tid >> 6;
    if (lane == 0) { sh[w] = s; sh[4 + w] = ss; }
    __syncthreads();
    if (tid == 0) {
        float S_ = sh[0] + sh[1] + sh[2] + sh[3];
        float SSv = sh[4] + sh[5] + sh[6] + sh[7];
        float mean = S_ * (1.f / BN_CNT);
        float var  = SSv * (1.f / BN_CNT) - mean * mean;
        float rstd = rsqrtf(var + EPSV);
        A2[c] = rstd * ag[c];
        B2[c] = ab[c] - mean * rstd * ag[c];
    }
}

// ---------------- final BN + ReLU in-place on d_out ------------------------
__global__ __launch_bounds__(256) void k_bnrelu(float* __restrict__ out,
                                                const float* __restrict__ A2,
                                                const float* __restrict__ B2) {
    int gid = blockIdx.x * 256 + threadIdx.x;
    int c = (gid >> 12) & 127;
    float v = out[gid];
    out[gid] = fmaxf(fmaf(A2[c], v, B2[c]), 0.f);
}

// ---------------------------------------------------------------------------
extern "C" void kernel_launch(void* const* d_in, const int* in_sizes, int n_in,
                              void* d_out, int out_size, void* d_ws, size_t ws_size,
                              hipStream_t stream) {
    (void)in_sizes; (void)n_in; (void)out_size; (void)ws_size;
    const float* x   = (const float*)d_in[0];
    const float* pcd = (const float*)d_in[1];
    const float* W   = (const float*)d_in[2];
    const float* kg  = (const float*)d_in[3];
    const float* kb  = (const float*)d_in[4];
    const float* vg  = (const float*)d_in[5];
    const float* vb  = (const float*)d_in[6];
    const float* R   = (const float*)d_in[7];
    const float* t   = (const float*)d_in[8];
    const float* cw  = (const float*)d_in[9];
    const float* cb  = (const float*)d_in[10];
    const float* ag  = (const float*)d_in[11];
    const float* ab  = (const float*)d_in[12];
    float* out = (float*)d_out;
    char* ws = (char*)d_ws;

    // workspace layout (bytes), total 57,675,776 (same as passing round)
    float* kv   = (float*)(ws + 0);            // 19,922,944
    int*   base = (int*)  (ws + 19922944ULL);  //  1,048,576
    float* frac = (float*)(ws + 20971520ULL);  //  3,145,728
    float* A    = (float*)(ws + 24117248ULL);  //  1,024
    float* Bv   = (float*)(ws + 24118272ULL);  //  1,024
    float* A2   = (float*)(ws + 24119296ULL);  //  1,024
    float* B2   = (float*)(ws + 24120320ULL);  //  1,024
    float* z_b  = (float*)(ws + 24121344ULL);  // 16,777,216 [h][cell][16]
    float* zc_b = (float*)(ws + 40898560ULL);  // 16,777,216 [h][cell][16]

    k_gemm<<<dim3(10, 16, BB), 256, 0, stream>>>(x, W, kv);
    k_stats_kv<<<dim3(CC), 256, 0, stream>>>(kv, kg, kb, vg, vb, A, Bv);
    k_prep<<<dim3(PTS / 256), 256, 0, stream>>>(kv, pcd, A, Bv, R, t, base, frac);

    for (int b = 0; b < BB; ++b) {
        hipMemsetAsync(z_b, 0, (size_t)16777216, stream);
        k_splat<<<dim3(BPT / 256, 8), 256, 0, stream>>>(kv, A, Bv, base, frac, z_b, b);
        k_conv<<<dim3(SS, 2, HH), 256, 0, stream>>>(z_b, cw, cb, zc_b);
        k_slice<<<dim3(BPT / 256, 4), 256, 0, stream>>>(base, frac, zc_b, out, b);
    }

    k_stats2<<<dim3(HH * FF), 256, 0, stream>>>(out, ag, ab, A2, B2);
    k_bnrelu<<<dim3((BB * HH * FF * NP) / 256), 256, 0, stream>>>(out, A2, B2);
}

// Round 4
// 1805.884 us; speedup vs baseline: 1.7753x; 1.5899x over previous
//
#include <hip/hip_runtime.h>
#include <cstddef>
#include <cstdint>

#define BB 8
#define MD 256
#define NP 4096
#define HH 8
#define FF 16
#define SS 32
#define S3 32768
#define CC 152      // H*(F+3)
#define KC 24       // H*3
#define PTS (BB*HH*NP)   // 262144
#define BPT (HH*NP)      // points per batch = 32768
#define BN_CNT (BB*NP)   // 32768
#define EPSV 1e-5f

// -------- GEMM: kv[b,o,n] = sum_m W[o,m] * x[b,m,n]; 16 oc per block -------
__global__ __launch_bounds__(256) void k_gemm(const float* __restrict__ x,
                                              const float* __restrict__ W,
                                              float* __restrict__ kv) {
    int oc0 = blockIdx.x * 16;          // 10 blocks * 16 = 160 (guard >=152)
    int nt  = blockIdx.y;               // 16 n-tiles
    int b   = blockIdx.z;
    int tid = threadIdx.x;
    int n = nt * 256 + tid;

    float acc[16];
#pragma unroll
    for (int r = 0; r < 16; ++r) acc[r] = 0.f;
    const float* xb = x + (size_t)b * MD * NP + n;
#pragma unroll 4
    for (int m = 0; m < MD; ++m) {
        float xv = xb[(size_t)m * NP];
#pragma unroll
        for (int r = 0; r < 16; ++r) {
            int rr = (oc0 + r < CC) ? (oc0 + r) : (CC - 1);   // clamp W row (uniform)
            acc[r] = fmaf(W[(size_t)rr * MD + m], xv, acc[r]);
        }
    }
#pragma unroll
    for (int r = 0; r < 16; ++r)
        if (oc0 + r < CC)
            kv[((size_t)b * CC + oc0 + r) * NP + n] = acc[r];
}

// ------------- BN stats over (B,N) for all 152 kv channels -----------------
__global__ __launch_bounds__(256) void k_stats_kv(const float* __restrict__ kv,
                                                  const float* __restrict__ kg,
                                                  const float* __restrict__ kb,
                                                  const float* __restrict__ vg,
                                                  const float* __restrict__ vb,
                                                  float* __restrict__ A,
                                                  float* __restrict__ Bv) {
    int o = blockIdx.x, tid = threadIdx.x;
    float s = 0.f, ss = 0.f;
    for (int b = 0; b < BB; ++b) {
        const float* p = kv + ((size_t)b * CC + o) * NP;
        for (int n = tid; n < NP; n += 256) { float v = p[n]; s += v; ss = fmaf(v, v, ss); }
    }
#pragma unroll
    for (int off = 32; off > 0; off >>= 1) { s += __shfl_down(s, off); ss += __shfl_down(ss, off); }
    __shared__ float sh[8];
    int lane = tid & 63, w = tid >> 6;
    if (lane == 0) { sh[w] = s; sh[4 + w] = ss; }
    __syncthreads();
    if (tid == 0) {
        float S_ = sh[0] + sh[1] + sh[2] + sh[3];
        float SSv = sh[4] + sh[5] + sh[6] + sh[7];
        float mean = S_ * (1.f / BN_CNT);
        float var  = SSv * (1.f / BN_CNT) - mean * mean;
        float rstd = rsqrtf(var + EPSV);
        float g  = (o < KC) ? kg[o] : vg[o - KC];
        float be = (o < KC) ? kb[o] : vb[o - KC];
        A[o]  = rstd * g;
        Bv[o] = be - mean * rstd * g;
    }
}

// --- per-point: BN keys -> affine -> tanh -> idx/frac; also emit vals[.,16] -
__global__ __launch_bounds__(256) void k_prep(const float* __restrict__ kv,
                                              const float* __restrict__ pcd,
                                              const float* __restrict__ A,
                                              const float* __restrict__ Bv,
                                              const float* __restrict__ R,
                                              const float* __restrict__ t,
                                              int* __restrict__ base,
                                              float* __restrict__ frac,
                                              float* __restrict__ vals) {
    int gid = blockIdx.x * 256 + threadIdx.x;
    int b = gid >> 15, h = (gid >> 12) & 7, n = gid & 4095;

    float p[3];
#pragma unroll
    for (int i = 0; i < 3; ++i) {
        int c = h * 3 + i;
        float v = kv[((size_t)b * CC + c) * NP + n];
        p[i] = pcd[((size_t)b * 3 + i) * NP + n] + fmaf(A[c], v, Bv[c]);
    }
    int fl[3]; float fr[3];
#pragma unroll
    for (int i = 0; i < 3; ++i) {
        float key = R[h * 9 + i * 3 + 0] * p[0] + R[h * 9 + i * 3 + 1] * p[1] +
                    R[h * 9 + i * 3 + 2] * p[2] + t[h * 3 + i];
        float lat = tanhf(key);
        float pos = (lat + 1.f) * 0.5f * (SS - 1);
        float flf = fminf(fmaxf(floorf(pos), 0.f), (float)(SS - 2));
        fr[i] = pos - flf;
        fl[i] = (int)flf;
    }
    base[gid] = (fl[0] * SS + fl[1]) * SS + fl[2];
    frac[gid]           = fr[0];
    frac[PTS + gid]     = fr[1];
    frac[2 * PTS + gid] = fr[2];

    // BN-normalized values, [point][16] layout for the splat gather
    float4* vo = (float4*)(vals + (size_t)gid * 16);
#pragma unroll
    for (int q = 0; q < 4; ++q) {
        float4 v;
        float* vv = (float*)&v;
#pragma unroll
        for (int j = 0; j < 4; ++j) {
            int c = KC + h * FF + q * 4 + j;
            vv[j] = fmaf(A[c], kv[((size_t)b * CC + c) * NP + n], Bv[c]);
        }
        vo[q] = v;
    }
}

// --- binned splat: block per (x-slab 0..30, h); LDS 2-plane accumulation ---
__global__ __launch_bounds__(256) void k_splat(const int* __restrict__ base,
                                               const float* __restrict__ frac,
                                               const float* __restrict__ vals,
                                               float* __restrict__ buf0,
                                               float* __restrict__ buf1, int b) {
    __shared__ float zl[2][1024][16];        // 128 KB: planes {x, x+1}
    __shared__ unsigned short list[4096];    // 8 KB
    __shared__ int cnt;
    int x = blockIdx.x;    // 0..30
    int h = blockIdx.y;
    int tid = threadIdx.x;

    float4 zero4 = make_float4(0.f, 0.f, 0.f, 0.f);
    float4* zl4 = (float4*)zl;
    for (int i = tid; i < 8192; i += 256) zl4[i] = zero4;
    if (tid == 0) cnt = 0;
    __syncthreads();

    int gb = b * BPT + h * NP;
    for (int p = tid; p < NP; p += 256) {
        int bs = base[gb + p];
        if ((bs >> 10) == x) { int s = atomicAdd(&cnt, 1); list[s] = (unsigned short)p; }
    }
    __syncthreads();
    int m = cnt;

    int pl  = tid >> 7;          // which of 2 points per pass
    int idx = tid & 127;
    int cor = idx >> 4, ch = idx & 15;
    int dxb = (cor >> 2) & 1, dyb = (cor >> 1) & 1, dzb = cor & 1;
    for (int i0 = 0; i0 < m; i0 += 2) {
        int i = i0 + pl;
        if (i < m) {
            int p = list[i];
            int g = gb + p;
            int bs = base[g];
            float fx = frac[g], fy = frac[PTS + g], fz = frac[2 * PTS + g];
            float w = (dxb ? fx : 1.f - fx) * (dyb ? fy : 1.f - fy) * (dzb ? fz : 1.f - fz);
            float v = vals[(size_t)g * 16 + ch];
            int yz = (bs & 1023) + dyb * 32 + dzb;
            atomicAdd(&zl[dxb][yz][ch], w * v);
        }
    }
    __syncthreads();

    // plane x -> buf0[h][x], plane x+1 -> buf1[h][x+1]; full planes, no memset
    size_t o0 = ((size_t)h * 32 + x) * 4096;       // float4 units
    size_t o1 = ((size_t)h * 32 + x + 1) * 4096;
    float4* b0 = (float4*)buf0;
    float4* b1 = (float4*)buf1;
    for (int i = tid; i < 4096; i += 256) {
        b0[o0 + i] = zl4[i];
        b1[o1 + i] = zl4[4096 + i];
    }
}

// ---- merge: z[p] = buf0[p] + buf1[p] (p=1..30), z[31] = buf1[31]; into buf0
__global__ __launch_bounds__(256) void k_merge(float* __restrict__ buf0,
                                               const float* __restrict__ buf1) {
    int i = blockIdx.x * 256 + threadIdx.x;   // float4 index over 8h*31p*4096
    int hp = i >> 12;
    int h = hp / 31, p = hp % 31 + 1;
    int q = i & 4095;
    size_t o = (((size_t)h * 32 + p) << 12) + q;
    float4 a = ((const float4*)buf1)[o];
    if (p < 31) {
        float4 c = ((const float4*)buf0)[o];
        a.x += c.x; a.y += c.y; a.z += c.z; a.w += c.w;
    }
    ((float4*)buf0)[o] = a;
}

// ---- grouped 3x3x3 conv, one batch; z/zc layout [h][cell][16] -------------
__global__ __launch_bounds__(256) void k_conv(const float* __restrict__ z,
                                              const float* __restrict__ cw,
                                              const float* __restrict__ cb,
                                              float* __restrict__ zc) {
    __shared__ float z_l[4][3][18][34];   // [ci][x-1..x+1][y half + halo][z pad]
    __shared__ float w_l[16 * 108];       // [fo][ci*27 + d]
    int xs = blockIdx.x;      // 0..31
    int yh = blockIdx.y;      // 0..1
    int h  = blockIdx.z;
    int tid = threadIdx.x;
    int zp = tid & 31;
    int yl = tid >> 5;        // 0..7 -> owns y = yh*16 + yl*2 + {0,1}

    float acc[16][2];
#pragma unroll
    for (int fo = 0; fo < 16; ++fo) { acc[fo][0] = 0.f; acc[fo][1] = 0.f; }

    for (int chunk = 0; chunk < 4; ++chunk) {
        int ci0 = chunk * 4;
        __syncthreads();
        for (int i = tid; i < 3 * 18 * 34; i += 256) {
            int dxi = i / 612, rem = i % 612;
            int yy = rem / 34, zi = rem % 34;
            int gx = xs + dxi - 1, gy = yh * 16 + yy - 1, gz = zi - 1;
            float4 v = make_float4(0.f, 0.f, 0.f, 0.f);
            if (gx >= 0 && gx < SS && gy >= 0 && gy < SS && gz >= 0 && gz < SS)
                v = *reinterpret_cast<const float4*>(
                        &z[((size_t)h * S3 + (gx * 1024 + gy * 32 + gz)) * FF + ci0]);
            z_l[0][dxi][yy][zi] = v.x;
            z_l[1][dxi][yy][zi] = v.y;
            z_l[2][dxi][yy][zi] = v.z;
            z_l[3][dxi][yy][zi] = v.w;
        }
        for (int i = tid; i < 16 * 108; i += 256)
            w_l[i] = cw[((size_t)(h * 16 + i / 108) * 16 + ci0) * 27 + (i % 108)];
        __syncthreads();

#pragma unroll 1
        for (int ci = 0; ci < 4; ++ci) {
#pragma unroll 1
            for (int dx = 0; dx < 3; ++dx) {
#pragma unroll
                for (int dy = 0; dy < 3; ++dy) {
#pragma unroll
                    for (int dz = 0; dz < 3; ++dz) {
                        float zv0 = z_l[ci][dx][yl * 2 + 0 + dy][zp + dz];
                        float zv1 = z_l[ci][dx][yl * 2 + 1 + dy][zp + dz];
                        int wbase = ci * 27 + dx * 9 + dy * 3 + dz;
#pragma unroll
                        for (int fo = 0; fo < 16; ++fo) {
                            float wv = w_l[fo * 108 + wbase];
                            acc[fo][0] = fmaf(wv, zv0, acc[fo][0]);
                            acc[fo][1] = fmaf(wv, zv1, acc[fo][1]);
                        }
                    }
                }
            }
        }
    }
#pragma unroll
    for (int cy = 0; cy < 2; ++cy) {
        int cell = xs * 1024 + (yh * 16 + yl * 2 + cy) * 32 + zp;
        float* dst = zc + ((size_t)h * S3 + cell) * FF;
#pragma unroll
        for (int q = 0; q < 4; ++q) {
            float4 v;
            v.x = acc[q * 4 + 0][cy] + cb[h * 16 + q * 4 + 0];
            v.y = acc[q * 4 + 1][cy] + cb[h * 16 + q * 4 + 1];
            v.z = acc[q * 4 + 2][cy] + cb[h * 16 + q * 4 + 2];
            v.w = acc[q * 4 + 3][cy] + cb[h * 16 + q * 4 + 3];
            *reinterpret_cast<float4*>(&dst[q * 4]) = v;
        }
    }
}

// --- slice (one batch): thread per (point, fo-quad); zc [h][cell][16] ------
__global__ __launch_bounds__(256) void k_slice(const int* __restrict__ base,
                                               const float* __restrict__ frac,
                                               const float* __restrict__ zc,
                                               float* __restrict__ out, int b) {
    int lid = blockIdx.x * 256 + threadIdx.x;   // 0..BPT-1
    int foq = blockIdx.y;                       // 0..3
    int h = lid >> 12, n = lid & 4095;
    int gid = b * BPT + lid;
    int bs = base[gid];
    float fx = frac[gid], fy = frac[PTS + gid], fz = frac[2 * PTS + gid];
    float wx[2] = {1.f - fx, fx}, wy[2] = {1.f - fy, fy}, wz[2] = {1.f - fz, fz};
    const float* zb = zc + (size_t)h * S3 * FF + foq * 4;

    float a0 = 0.f, a1 = 0.f, a2 = 0.f, a3 = 0.f;
#pragma unroll
    for (int dx = 0; dx < 2; ++dx)
#pragma unroll
    for (int dy = 0; dy < 2; ++dy)
#pragma unroll
    for (int dz = 0; dz < 2; ++dz) {
        int cell = bs + dx * (SS * SS) + dy * SS + dz;
        float w = wx[dx] * wy[dy] * wz[dz];
        float4 v = *reinterpret_cast<const float4*>(&zb[(size_t)cell * FF]);
        a0 = fmaf(v.x, w, a0); a1 = fmaf(v.y, w, a1);
        a2 = fmaf(v.z, w, a2); a3 = fmaf(v.w, w, a3);
    }
    size_t ob = ((size_t)b * (HH * FF) + h * FF + foq * 4) * NP + n;
    out[ob]          = a0;
    out[ob + NP]     = a1;
    out[ob + 2 * NP] = a2;
    out[ob + 3 * NP] = a3;
}

// ------------- BN stats over (B,N) for the 128 sliced channels -------------
__global__ __launch_bounds__(256) void k_stats2(const float* __restrict__ out,
                                                const float* __restrict__ ag,
                                                const float* __restrict__ ab,
                                                float* __restrict__ A2,
                                                float* __restrict__ B2) {
    int c = blockIdx.x, tid = threadIdx.x;
    float s = 0.f, ss = 0.f;
    for (int b = 0; b < BB; ++b) {
        const float* p = out + ((size_t)b * (HH * FF) + c) * NP;
        for (int n = tid; n < NP; n += 256) { float v = p[n]; s += v; ss = fmaf(v, v, ss); }
    }
#pragma unroll
    for (int off = 32; off > 0; off >>= 1) { s += __shfl_down(s, off); ss += __shfl_down(ss, off); }
    __shared__ float sh[8];
    int lane = tid & 63, w = tid >> 6;
    if (lane == 0) { sh[w] = s; sh[4 + w] = ss; }
    __syncthreads();
    if (tid == 0) {
        float S_ = sh[0] + sh[1] + sh[2] + sh[3];
        float SSv = sh[4] + sh[5] + sh[6] + sh[7];
        float mean = S_ * (1.f / BN_CNT);
        float var  = SSv * (1.f / BN_CNT) - mean * mean;
        float rstd = rsqrtf(var + EPSV);
        A2[c] = rstd * ag[c];
        B2[c] = ab[c] - mean * rstd * ag[c];
    }
}

// ---------------- final BN + ReLU in-place on d_out ------------------------
__global__ __launch_bounds__(256) void k_bnrelu(float* __restrict__ out,
                                                const float* __restrict__ A2,
                                                const float* __restrict__ B2) {
    int gid = blockIdx.x * 256 + threadIdx.x;
    int c = (gid >> 12) & 127;
    float v = out[gid];
    out[gid] = fmaxf(fmaf(A2[c], v, B2[c]), 0.f);
}

// ---------------------------------------------------------------------------
extern "C" void kernel_launch(void* const* d_in, const int* in_sizes, int n_in,
                              void* d_out, int out_size, void* d_ws, size_t ws_size,
                              hipStream_t stream) {
    (void)in_sizes; (void)n_in; (void)out_size; (void)ws_size;
    const float* x   = (const float*)d_in[0];
    const float* pcd = (const float*)d_in[1];
    const float* W   = (const float*)d_in[2];
    const float* kg  = (const float*)d_in[3];
    const float* kb  = (const float*)d_in[4];
    const float* vg  = (const float*)d_in[5];
    const float* vb  = (const float*)d_in[6];
    const float* R   = (const float*)d_in[7];
    const float* t   = (const float*)d_in[8];
    const float* cw  = (const float*)d_in[9];
    const float* cb  = (const float*)d_in[10];
    const float* ag  = (const float*)d_in[11];
    const float* ab  = (const float*)d_in[12];
    float* out = (float*)d_out;
    char* ws = (char*)d_ws;

    // workspace layout (bytes), total 57,675,776 (same proven-safe footprint)
    float* kv   = (float*)(ws + 0);            // 19,922,944; dead after k_prep
    float* buf0 = kv;                          // 16,777,216 alias (batch loop)
    int*   base = (int*)  (ws + 19922944ULL);  //  1,048,576
    float* frac = (float*)(ws + 20971520ULL);  //  3,145,728
    float* A    = (float*)(ws + 24117248ULL);  //  1,024
    float* Bv   = (float*)(ws + 24118272ULL);  //  1,024
    float* A2   = (float*)(ws + 24119296ULL);  //  1,024
    float* B2   = (float*)(ws + 24120320ULL);  //  1,024
    float* vals = (float*)(ws + 24121344ULL);  // 16,777,216 [point][16]
    float* buf1 = (float*)(ws + 40898560ULL);  // 16,777,216
    float* zc   = buf1;                        // alias: conv writes after merge

    k_gemm<<<dim3(10, 16, BB), 256, 0, stream>>>(x, W, kv);
    k_stats_kv<<<dim3(CC), 256, 0, stream>>>(kv, kg, kb, vg, vb, A, Bv);
    k_prep<<<dim3(PTS / 256), 256, 0, stream>>>(kv, pcd, A, Bv, R, t, base, frac, vals);

    for (int b = 0; b < BB; ++b) {
        k_splat<<<dim3(31, 8), 256, 0, stream>>>(base, frac, vals, buf0, buf1, b);
        k_merge<<<dim3(3968), 256, 0, stream>>>(buf0, buf1);
        k_conv<<<dim3(SS, 2, HH), 256, 0, stream>>>(buf0, cw, cb, zc);
        k_slice<<<dim3(BPT / 256, 4), 256, 0, stream>>>(base, frac, zc, out, b);
    }

    k_stats2<<<dim3(HH * FF), 256, 0, stream>>>(out, ag, ab, A2, B2);
    k_bnrelu<<<dim3((BB * HH * FF * NP) / 256), 256, 0, stream>>>(out, A2, B2);
}

// Round 5
// 1667.411 us; speedup vs baseline: 1.9227x; 1.0830x over previous
//
#include <hip/hip_runtime.h>
#include <cstddef>
#include <cstdint>

#define BB 8
#define MD 256
#define NP 4096
#define HH 8
#define FF 16
#define SS 32
#define S3 32768
#define CC 152      // H*(F+3)
#define KC 24       // H*3
#define PTS (BB*HH*NP)   // 262144
#define BPT (HH*NP)      // points per batch = 32768
#define BN_CNT (BB*NP)   // 32768
#define EPSV 1e-5f
#define ZSTRF (HH*S3*FF)     // per-batch lattice floats = 4,194,304
#define ZSTRF4 (ZSTRF/4)     // in float4 units

// -------- GEMM: kv[b,o,n] = sum_m W[o,m] * x[b,m,n]; 16 oc per block -------
__global__ __launch_bounds__(256) void k_gemm(const float* __restrict__ x,
                                              const float* __restrict__ W,
                                              float* __restrict__ kv) {
    int oc0 = blockIdx.x * 16;          // 10 blocks * 16 = 160 (guard >=152)
    int nt  = blockIdx.y;               // 16 n-tiles
    int b   = blockIdx.z;
    int tid = threadIdx.x;
    int n = nt * 256 + tid;

    float acc[16];
#pragma unroll
    for (int r = 0; r < 16; ++r) acc[r] = 0.f;
    const float* xb = x + (size_t)b * MD * NP + n;
#pragma unroll 4
    for (int m = 0; m < MD; ++m) {
        float xv = xb[(size_t)m * NP];
#pragma unroll
        for (int r = 0; r < 16; ++r) {
            int rr = (oc0 + r < CC) ? (oc0 + r) : (CC - 1);   // clamp W row (uniform)
            acc[r] = fmaf(W[(size_t)rr * MD + m], xv, acc[r]);
        }
    }
#pragma unroll
    for (int r = 0; r < 16; ++r)
        if (oc0 + r < CC)
            kv[((size_t)b * CC + oc0 + r) * NP + n] = acc[r];
}

// ------------- BN stats over (B,N) for all 152 kv channels -----------------
__global__ __launch_bounds__(256) void k_stats_kv(const float* __restrict__ kv,
                                                  const float* __restrict__ kg,
                                                  const float* __restrict__ kb,
                                                  const float* __restrict__ vg,
                                                  const float* __restrict__ vb,
                                                  float* __restrict__ A,
                                                  float* __restrict__ Bv) {
    int o = blockIdx.x, tid = threadIdx.x;
    float s = 0.f, ss = 0.f;
    for (int b = 0; b < BB; ++b) {
        const float* p = kv + ((size_t)b * CC + o) * NP;
        for (int n = tid; n < NP; n += 256) { float v = p[n]; s += v; ss = fmaf(v, v, ss); }
    }
#pragma unroll
    for (int off = 32; off > 0; off >>= 1) { s += __shfl_down(s, off); ss += __shfl_down(ss, off); }
    __shared__ float sh[8];
    int lane = tid & 63, w = tid >> 6;
    if (lane == 0) { sh[w] = s; sh[4 + w] = ss; }
    __syncthreads();
    if (tid == 0) {
        float S_ = sh[0] + sh[1] + sh[2] + sh[3];
        float SSv = sh[4] + sh[5] + sh[6] + sh[7];
        float mean = S_ * (1.f / BN_CNT);
        float var  = SSv * (1.f / BN_CNT) - mean * mean;
        float rstd = rsqrtf(var + EPSV);
        float g  = (o < KC) ? kg[o] : vg[o - KC];
        float be = (o < KC) ? kb[o] : vb[o - KC];
        A[o]  = rstd * g;
        Bv[o] = be - mean * rstd * g;
    }
}

// --- per-point: BN keys -> affine -> tanh -> idx/frac; also emit vals[.,16] -
__global__ __launch_bounds__(256) void k_prep(const float* __restrict__ kv,
                                              const float* __restrict__ pcd,
                                              const float* __restrict__ A,
                                              const float* __restrict__ Bv,
                                              const float* __restrict__ R,
                                              const float* __restrict__ t,
                                              int* __restrict__ base,
                                              float* __restrict__ frac,
                                              float* __restrict__ vals) {
    int gid = blockIdx.x * 256 + threadIdx.x;
    int b = gid >> 15, h = (gid >> 12) & 7, n = gid & 4095;

    float p[3];
#pragma unroll
    for (int i = 0; i < 3; ++i) {
        int c = h * 3 + i;
        float v = kv[((size_t)b * CC + c) * NP + n];
        p[i] = pcd[((size_t)b * 3 + i) * NP + n] + fmaf(A[c], v, Bv[c]);
    }
    int fl[3]; float fr[3];
#pragma unroll
    for (int i = 0; i < 3; ++i) {
        float key = R[h * 9 + i * 3 + 0] * p[0] + R[h * 9 + i * 3 + 1] * p[1] +
                    R[h * 9 + i * 3 + 2] * p[2] + t[h * 3 + i];
        float lat = tanhf(key);
        float pos = (lat + 1.f) * 0.5f * (SS - 1);
        float flf = fminf(fmaxf(floorf(pos), 0.f), (float)(SS - 2));
        fr[i] = pos - flf;
        fl[i] = (int)flf;
    }
    base[gid] = (fl[0] * SS + fl[1]) * SS + fl[2];
    frac[gid]           = fr[0];
    frac[PTS + gid]     = fr[1];
    frac[2 * PTS + gid] = fr[2];

    // BN-normalized values, [point][16] layout for the splat gather
    float4* vo = (float4*)(vals + (size_t)gid * 16);
#pragma unroll
    for (int q = 0; q < 4; ++q) {
        float4 v;
        float* vv = (float*)&v;
#pragma unroll
        for (int j = 0; j < 4; ++j) {
            int c = KC + h * FF + q * 4 + j;
            vv[j] = fmaf(A[c], kv[((size_t)b * CC + c) * NP + n], Bv[c]);
        }
        vo[q] = v;
    }
}

// --- binned splat: block per (x-slab 0..30, h, bq); LDS 2-plane accum ------
__global__ __launch_bounds__(256) void k_splat(const int* __restrict__ base,
                                               const float* __restrict__ frac,
                                               const float* __restrict__ vals,
                                               float* __restrict__ buf0,
                                               float* __restrict__ buf1, int b0) {
    __shared__ float zl[2][1024][16];        // 128 KB: planes {x, x+1}
    __shared__ unsigned short list[4096];    // 8 KB
    __shared__ int cnt;
    int x = blockIdx.x;    // 0..30
    int h = blockIdx.y;
    int bq = blockIdx.z;
    int b = b0 + bq;
    int tid = threadIdx.x;

    float4 zero4 = make_float4(0.f, 0.f, 0.f, 0.f);
    float4* zl4 = (float4*)zl;
    for (int i = tid; i < 8192; i += 256) zl4[i] = zero4;
    if (tid == 0) cnt = 0;
    __syncthreads();

    int gb = b * BPT + h * NP;
    for (int p = tid; p < NP; p += 256) {
        int bs = base[gb + p];
        if ((bs >> 10) == x) { int s = atomicAdd(&cnt, 1); list[s] = (unsigned short)p; }
    }
    __syncthreads();
    int m = cnt;

    int pl  = tid >> 7;          // which of 2 points per pass
    int idx = tid & 127;
    int cor = idx >> 4, ch = idx & 15;
    int dxb = (cor >> 2) & 1, dyb = (cor >> 1) & 1, dzb = cor & 1;
    for (int i0 = 0; i0 < m; i0 += 2) {
        int i = i0 + pl;
        if (i < m) {
            int p = list[i];
            int g = gb + p;
            int bs = base[g];
            float fx = frac[g], fy = frac[PTS + g], fz = frac[2 * PTS + g];
            float w = (dxb ? fx : 1.f - fx) * (dyb ? fy : 1.f - fy) * (dzb ? fz : 1.f - fz);
            float v = vals[(size_t)g * 16 + ch];
            int yz = (bs & 1023) + dyb * 32 + dzb;
            atomicAdd(&zl[dxb][yz][ch], w * v);
        }
    }
    __syncthreads();

    // plane x -> buf0[bq][h][x], plane x+1 -> buf1[bq][h][x+1]
    size_t o0 = (size_t)bq * ZSTRF4 + ((size_t)h * 32 + x) * 4096;       // float4 units
    size_t o1 = (size_t)bq * ZSTRF4 + ((size_t)h * 32 + x + 1) * 4096;
    float4* bp0 = (float4*)buf0;
    float4* bp1 = (float4*)buf1;
    for (int i = tid; i < 4096; i += 256) {
        bp0[o0 + i] = zl4[i];
        bp1[o1 + i] = zl4[4096 + i];
    }
}

// ---- merge: z[p] = buf0[p] + buf1[p] (p=1..30), z[31] = buf1[31]; into buf0
__global__ __launch_bounds__(256) void k_merge(float* __restrict__ buf0,
                                               const float* __restrict__ buf1) {
    int i = blockIdx.x * 256 + threadIdx.x;   // float4 index over 8h*31p*4096
    int bq = blockIdx.y;
    int hp = i >> 12;
    int h = hp / 31, p = hp % 31 + 1;
    int q = i & 4095;
    size_t o = (size_t)bq * ZSTRF4 + (((size_t)h * 32 + p) << 12) + q;
    float4 a = ((const float4*)buf1)[o];
    if (p < 31) {
        float4 c = ((const float4*)buf0)[o];
        a.x += c.x; a.y += c.y; a.z += c.z; a.w += c.w;
    }
    ((float4*)buf0)[o] = a;
}

// ---- grouped 3x3x3 conv; y-split x4; z/zc layout [bq][h][cell][16] --------
__global__ __launch_bounds__(256) void k_conv(const float* __restrict__ z,
                                              const float* __restrict__ cw,
                                              const float* __restrict__ cb,
                                              float* __restrict__ zc) {
    __shared__ float z_l[4][3][10][34];   // [ci][x-1..x+1][8 y + halo][z pad]
    __shared__ float w_l[16 * 108];       // [fo][ci*27 + d]
    int xs = blockIdx.x;      // 0..31
    int yq = blockIdx.y;      // 0..3
    int g  = blockIdx.z;      // h + 8*bq
    int h  = g & 7;
    int bq = g >> 3;
    int tid = threadIdx.x;
    int zp = tid & 31;
    int yl = tid >> 5;        // 0..7 -> owns y = yq*8 + yl

    const float* zb = z + (size_t)bq * ZSTRF;
    float* zcb = zc + (size_t)bq * ZSTRF;

    float acc[16];
#pragma unroll
    for (int fo = 0; fo < 16; ++fo) acc[fo] = 0.f;

    for (int chunk = 0; chunk < 4; ++chunk) {
        int ci0 = chunk * 4;
        __syncthreads();
        // stage z slab as float4 (4 input channels), with zero halo
        for (int i = tid; i < 3 * 10 * 34; i += 256) {
            int dxi = i / 340, rem = i % 340;
            int yy = rem / 34, zi = rem % 34;
            int gx = xs + dxi - 1, gy = yq * 8 + yy - 1, gz = zi - 1;
            float4 v = make_float4(0.f, 0.f, 0.f, 0.f);
            if (gx >= 0 && gx < SS && gy >= 0 && gy < SS && gz >= 0 && gz < SS)
                v = *reinterpret_cast<const float4*>(
                        &zb[((size_t)h * S3 + (gx * 1024 + gy * 32 + gz)) * FF + ci0]);
            z_l[0][dxi][yy][zi] = v.x;
            z_l[1][dxi][yy][zi] = v.y;
            z_l[2][dxi][yy][zi] = v.z;
            z_l[3][dxi][yy][zi] = v.w;
        }
        for (int i = tid; i < 16 * 108; i += 256)
            w_l[i] = cw[((size_t)(h * 16 + i / 108) * 16 + ci0) * 27 + (i % 108)];
        __syncthreads();

#pragma unroll 1
        for (int ci = 0; ci < 4; ++ci) {
#pragma unroll 1
            for (int dx = 0; dx < 3; ++dx) {
#pragma unroll
                for (int dy = 0; dy < 3; ++dy) {
#pragma unroll
                    for (int dz = 0; dz < 3; ++dz) {
                        float zv = z_l[ci][dx][yl + dy][zp + dz];
                        int wbase = ci * 27 + dx * 9 + dy * 3 + dz;
#pragma unroll
                        for (int fo = 0; fo < 16; ++fo)
                            acc[fo] = fmaf(w_l[fo * 108 + wbase], zv, acc[fo]);
                    }
                }
            }
        }
    }
    int cell = xs * 1024 + (yq * 8 + yl) * 32 + zp;
    float* dst = zcb + ((size_t)h * S3 + cell) * FF;
#pragma unroll
    for (int q = 0; q < 4; ++q) {
        float4 v;
        v.x = acc[q * 4 + 0] + cb[h * 16 + q * 4 + 0];
        v.y = acc[q * 4 + 1] + cb[h * 16 + q * 4 + 1];
        v.z = acc[q * 4 + 2] + cb[h * 16 + q * 4 + 2];
        v.w = acc[q * 4 + 3] + cb[h * 16 + q * 4 + 3];
        *reinterpret_cast<float4*>(&dst[q * 4]) = v;
    }
}

// --- slice: thread per (point, fo-quad); zc [bq][h][cell][16] --------------
__global__ __launch_bounds__(256) void k_slice(const int* __restrict__ base,
                                               const float* __restrict__ frac,
                                               const float* __restrict__ zc,
                                               float* __restrict__ out, int b0) {
    int lid = blockIdx.x * 256 + threadIdx.x;   // 0..BPT-1
    int foq = blockIdx.y;                       // 0..3
    int bq = blockIdx.z;
    int b = b0 + bq;
    int h = lid >> 12, n = lid & 4095;
    int gid = b * BPT + lid;
    int bs = base[gid];
    float fx = frac[gid], fy = frac[PTS + gid], fz = frac[2 * PTS + gid];
    float wx[2] = {1.f - fx, fx}, wy[2] = {1.f - fy, fy}, wz[2] = {1.f - fz, fz};
    const float* zb = zc + (size_t)bq * ZSTRF + (size_t)h * S3 * FF + foq * 4;

    float a0 = 0.f, a1 = 0.f, a2 = 0.f, a3 = 0.f;
#pragma unroll
    for (int dx = 0; dx < 2; ++dx)
#pragma unroll
    for (int dy = 0; dy < 2; ++dy)
#pragma unroll
    for (int dz = 0; dz < 2; ++dz) {
        int cell = bs + dx * (SS * SS) + dy * SS + dz;
        float w = wx[dx] * wy[dy] * wz[dz];
        float4 v = *reinterpret_cast<const float4*>(&zb[(size_t)cell * FF]);
        a0 = fmaf(v.x, w, a0); a1 = fmaf(v.y, w, a1);
        a2 = fmaf(v.z, w, a2); a3 = fmaf(v.w, w, a3);
    }
    size_t ob = ((size_t)b * (HH * FF) + h * FF + foq * 4) * NP + n;
    out[ob]          = a0;
    out[ob + NP]     = a1;
    out[ob + 2 * NP] = a2;
    out[ob + 3 * NP] = a3;
}

// ------------- BN stats over (B,N) for the 128 sliced channels -------------
__global__ __launch_bounds__(256) void k_stats2(const float* __restrict__ out,
                                                const float* __restrict__ ag,
                                                const float* __restrict__ ab,
                                                float* __restrict__ A2,
                                                float* __restrict__ B2) {
    int c = blockIdx.x, tid = threadIdx.x;
    float s = 0.f, ss = 0.f;
    for (int b = 0; b < BB; ++b) {
        const float* p = out + ((size_t)b * (HH * FF) + c) * NP;
        for (int n = tid; n < NP; n += 256) { float v = p[n]; s += v; ss = fmaf(v, v, ss); }
    }
#pragma unroll
    for (int off = 32; off > 0; off >>= 1) { s += __shfl_down(s, off); ss += __shfl_down(ss, off); }
    __shared__ float sh[8];
    int lane = tid & 63, w = tid >> 6;
    if (lane == 0) { sh[w] = s; sh[4 + w] = ss; }
    __syncthreads();
    if (tid == 0) {
        float S_ = sh[0] + sh[1] + sh[2] + sh[3];
        float SSv = sh[4] + sh[5] + sh[6] + sh[7];
        float mean = S_ * (1.f / BN_CNT);
        float var  = SSv * (1.f / BN_CNT) - mean * mean;
        float rstd = rsqrtf(var + EPSV);
        A2[c] = rstd * ag[c];
        B2[c] = ab[c] - mean * rstd * ag[c];
    }
}

// ---------------- final BN + ReLU in-place on d_out ------------------------
__global__ __launch_bounds__(256) void k_bnrelu(float* __restrict__ out,
                                                const float* __restrict__ A2,
                                                const float* __restrict__ B2) {
    int gid = blockIdx.x * 256 + threadIdx.x;
    int c = (gid >> 12) & 127;
    float v = out[gid];
    out[gid] = fmaxf(fmaf(A2[c], v, B2[c]), 0.f);
}

// ---------------------------------------------------------------------------
extern "C" void kernel_launch(void* const* d_in, const int* in_sizes, int n_in,
                              void* d_out, int out_size, void* d_ws, size_t ws_size,
                              hipStream_t stream) {
    (void)in_sizes; (void)n_in; (void)out_size;
    const float* x   = (const float*)d_in[0];
    const float* pcd = (const float*)d_in[1];
    const float* W   = (const float*)d_in[2];
    const float* kg  = (const float*)d_in[3];
    const float* kb  = (const float*)d_in[4];
    const float* vg  = (const float*)d_in[5];
    const float* vb  = (const float*)d_in[6];
    const float* R   = (const float*)d_in[7];
    const float* t   = (const float*)d_in[8];
    const float* cw  = (const float*)d_in[9];
    const float* cb  = (const float*)d_in[10];
    const float* ag  = (const float*)d_in[11];
    const float* ab  = (const float*)d_in[12];
    float* out = (float*)d_out;
    char* ws = (char*)d_ws;

    // fixed workspace region (40,898,560 B)
    float* kv   = (float*)(ws + 0);            // 19,922,944; dead after k_prep
    int*   base = (int*)  (ws + 19922944ULL);  //  1,048,576
    float* frac = (float*)(ws + 20971520ULL);  //  3,145,728
    float* A    = (float*)(ws + 24117248ULL);  //  1,024
    float* Bv   = (float*)(ws + 24118272ULL);  //  1,024
    float* A2   = (float*)(ws + 24119296ULL);  //  1,024
    float* B2   = (float*)(ws + 24120320ULL);  //  1,024
    float* vals = (float*)(ws + 24121344ULL);  // 16,777,216 [point][16]

    // batch-group size gated by ws_size (57.7 MB layout is proven-safe)
    int NB = 1;
    if (ws_size >= 40898560ULL + 4ULL * 33554432ULL)      NB = 4;  // 175,116,288
    else if (ws_size >= 40898560ULL + 2ULL * 33554432ULL) NB = 2;  // 108,007,424

    float *buf0, *buf1;
    if (NB == 1) {
        buf0 = kv;                              // alias (kv dead), as round 4
        buf1 = (float*)(ws + 40898560ULL);      // 16,777,216; zc aliases buf1
    } else {
        buf0 = (float*)(ws + 40898560ULL);              // NB * 16,777,216
        buf1 = buf0 + (size_t)NB * ZSTRF;               // NB * 16,777,216
    }

    k_gemm<<<dim3(10, 16, BB), 256, 0, stream>>>(x, W, kv);
    k_stats_kv<<<dim3(CC), 256, 0, stream>>>(kv, kg, kb, vg, vb, A, Bv);
    k_prep<<<dim3(PTS / 256), 256, 0, stream>>>(kv, pcd, A, Bv, R, t, base, frac, vals);

    for (int b0 = 0; b0 < BB; b0 += NB) {
        k_splat<<<dim3(31, 8, NB), 256, 0, stream>>>(base, frac, vals, buf0, buf1, b0);
        k_merge<<<dim3(3968, NB), 256, 0, stream>>>(buf0, buf1);
        k_conv<<<dim3(SS, 4, HH * NB), 256, 0, stream>>>(buf0, cw, cb, buf1);
        k_slice<<<dim3(BPT / 256, 4, NB), 256, 0, stream>>>(base, frac, buf1, out, b0);
    }

    k_stats2<<<dim3(HH * FF), 256, 0, stream>>>(out, ag, ab, A2, B2);
    k_bnrelu<<<dim3((BB * HH * FF * NP) / 256), 256, 0, stream>>>(out, A2, B2);
}

// Round 6
// 844.072 us; speedup vs baseline: 3.7982x; 1.9754x over previous
//
#include <hip/hip_runtime.h>
#include <cstddef>
#include <cstdint>

#define BB 8
#define MD 256
#define NP 4096
#define HH 8
#define FF 16
#define SS 32
#define S3 32768
#define CC 152      // H*(F+3)
#define KC 24       // H*3
#define PTS (BB*HH*NP)   // 262144
#define BPT (HH*NP)      // points per batch = 32768
#define BN_CNT (BB*NP)   // 32768
#define EPSV 1e-5f
#define ZSTRF (HH*S3*FF)     // per-batch lattice floats = 4,194,304
#define ZSTRF4 (ZSTRF/4)     // in float4 units

typedef __attribute__((ext_vector_type(8))) short short8v;
typedef __attribute__((ext_vector_type(4))) float f32x4;

__device__ __forceinline__ unsigned short f2bf(float f) {
    unsigned int u = __float_as_uint(f);
    unsigned int r = u + 0x7FFFu + ((u >> 16) & 1u);   // round-to-nearest-even
    return (unsigned short)(r >> 16);
}

// -------- GEMM: kv[b,o,n] = sum_m W[o,m] * x[b,m,n]; 16 oc per block -------
__global__ __launch_bounds__(256) void k_gemm(const float* __restrict__ x,
                                              const float* __restrict__ W,
                                              float* __restrict__ kv) {
    int oc0 = blockIdx.x * 16;
    int nt  = blockIdx.y;
    int b   = blockIdx.z;
    int tid = threadIdx.x;
    int n = nt * 256 + tid;

    float acc[16];
#pragma unroll
    for (int r = 0; r < 16; ++r) acc[r] = 0.f;
    const float* xb = x + (size_t)b * MD * NP + n;
#pragma unroll 4
    for (int m = 0; m < MD; ++m) {
        float xv = xb[(size_t)m * NP];
#pragma unroll
        for (int r = 0; r < 16; ++r) {
            int rr = (oc0 + r < CC) ? (oc0 + r) : (CC - 1);
            acc[r] = fmaf(W[(size_t)rr * MD + m], xv, acc[r]);
        }
    }
#pragma unroll
    for (int r = 0; r < 16; ++r)
        if (oc0 + r < CC)
            kv[((size_t)b * CC + oc0 + r) * NP + n] = acc[r];
}

// ------------- BN stats over (B,N) for all 152 kv channels -----------------
__global__ __launch_bounds__(256) void k_stats_kv(const float* __restrict__ kv,
                                                  const float* __restrict__ kg,
                                                  const float* __restrict__ kb,
                                                  const float* __restrict__ vg,
                                                  const float* __restrict__ vb,
                                                  float* __restrict__ A,
                                                  float* __restrict__ Bv) {
    int o = blockIdx.x, tid = threadIdx.x;
    float s = 0.f, ss = 0.f;
    for (int b = 0; b < BB; ++b) {
        const float* p = kv + ((size_t)b * CC + o) * NP;
        for (int n = tid; n < NP; n += 256) { float v = p[n]; s += v; ss = fmaf(v, v, ss); }
    }
#pragma unroll
    for (int off = 32; off > 0; off >>= 1) { s += __shfl_down(s, off); ss += __shfl_down(ss, off); }
    __shared__ float sh[8];
    int lane = tid & 63, w = tid >> 6;
    if (lane == 0) { sh[w] = s; sh[4 + w] = ss; }
    __syncthreads();
    if (tid == 0) {
        float S_ = sh[0] + sh[1] + sh[2] + sh[3];
        float SSv = sh[4] + sh[5] + sh[6] + sh[7];
        float mean = S_ * (1.f / BN_CNT);
        float var  = SSv * (1.f / BN_CNT) - mean * mean;
        float rstd = rsqrtf(var + EPSV);
        float g  = (o < KC) ? kg[o] : vg[o - KC];
        float be = (o < KC) ? kb[o] : vb[o - KC];
        A[o]  = rstd * g;
        Bv[o] = be - mean * rstd * g;
    }
}

// --- per-point: BN keys -> affine -> tanh -> idx/frac; also emit vals[.,16] -
__global__ __launch_bounds__(256) void k_prep(const float* __restrict__ kv,
                                              const float* __restrict__ pcd,
                                              const float* __restrict__ A,
                                              const float* __restrict__ Bv,
                                              const float* __restrict__ R,
                                              const float* __restrict__ t,
                                              int* __restrict__ base,
                                              float* __restrict__ frac,
                                              float* __restrict__ vals) {
    int gid = blockIdx.x * 256 + threadIdx.x;
    int b = gid >> 15, h = (gid >> 12) & 7, n = gid & 4095;

    float p[3];
#pragma unroll
    for (int i = 0; i < 3; ++i) {
        int c = h * 3 + i;
        float v = kv[((size_t)b * CC + c) * NP + n];
        p[i] = pcd[((size_t)b * 3 + i) * NP + n] + fmaf(A[c], v, Bv[c]);
    }
    int fl[3]; float fr[3];
#pragma unroll
    for (int i = 0; i < 3; ++i) {
        float key = R[h * 9 + i * 3 + 0] * p[0] + R[h * 9 + i * 3 + 1] * p[1] +
                    R[h * 9 + i * 3 + 2] * p[2] + t[h * 3 + i];
        float lat = tanhf(key);
        float pos = (lat + 1.f) * 0.5f * (SS - 1);
        float flf = fminf(fmaxf(floorf(pos), 0.f), (float)(SS - 2));
        fr[i] = pos - flf;
        fl[i] = (int)flf;
    }
    base[gid] = (fl[0] * SS + fl[1]) * SS + fl[2];
    frac[gid]           = fr[0];
    frac[PTS + gid]     = fr[1];
    frac[2 * PTS + gid] = fr[2];

    float4* vo = (float4*)(vals + (size_t)gid * 16);
#pragma unroll
    for (int q = 0; q < 4; ++q) {
        float4 v;
        float* vv = (float*)&v;
#pragma unroll
        for (int j = 0; j < 4; ++j) {
            int c = KC + h * FF + q * 4 + j;
            vv[j] = fmaf(A[c], kv[((size_t)b * CC + c) * NP + n], Bv[c]);
        }
        vo[q] = v;
    }
}

// ---- pack conv weights into MFMA A-fragment lane order (bf16) -------------
// K order: k_local = g*8+j; g=lane>>4: tap = 2m + (g>>1), ci = (g&1)*8 + j
__global__ __launch_bounds__(256) void k_wpack(const float* __restrict__ cw,
                                               unsigned short* __restrict__ wApack) {
    int gid = blockIdx.x * 256 + threadIdx.x;     // (h*14 + m)*64 + lane
    if (gid >= 8 * 14 * 64) return;
    int lane = gid & 63;
    int m = (gid >> 6) % 14;
    int h = gid / (14 * 64);
    int fo = lane & 15, g = lane >> 4;
    int tap = 2 * m + (g >> 1);
    int ci0 = (g & 1) * 8;
    unsigned short o[8];
#pragma unroll
    for (int j = 0; j < 8; ++j) {
        float w = (tap <= 26) ? cw[((size_t)(h * 16 + fo) * 16 + ci0 + j) * 27 + tap] : 0.f;
        o[j] = f2bf(w);
    }
    ushort4* dst = (ushort4*)(wApack + (size_t)gid * 8);
    dst[0] = make_ushort4(o[0], o[1], o[2], o[3]);
    dst[1] = make_ushort4(o[4], o[5], o[6], o[7]);
}

// --- binned splat: block per (x-slab 0..30, h, bq); LDS 2-plane accum ------
__global__ __launch_bounds__(256) void k_splat(const int* __restrict__ base,
                                               const float* __restrict__ frac,
                                               const float* __restrict__ vals,
                                               float* __restrict__ buf0,
                                               float* __restrict__ buf1, int b0) {
    __shared__ float zl[2][1024][16];
    __shared__ unsigned short list[4096];
    __shared__ int cnt;
    int x = blockIdx.x;
    int h = blockIdx.y;
    int bq = blockIdx.z;
    int b = b0 + bq;
    int tid = threadIdx.x;

    float4 zero4 = make_float4(0.f, 0.f, 0.f, 0.f);
    float4* zl4 = (float4*)zl;
    for (int i = tid; i < 8192; i += 256) zl4[i] = zero4;
    if (tid == 0) cnt = 0;
    __syncthreads();

    int gb = b * BPT + h * NP;
    for (int p = tid; p < NP; p += 256) {
        int bs = base[gb + p];
        if ((bs >> 10) == x) { int s = atomicAdd(&cnt, 1); list[s] = (unsigned short)p; }
    }
    __syncthreads();
    int m = cnt;

    int pl  = tid >> 7;
    int idx = tid & 127;
    int cor = idx >> 4, ch = idx & 15;
    int dxb = (cor >> 2) & 1, dyb = (cor >> 1) & 1, dzb = cor & 1;
    for (int i0 = 0; i0 < m; i0 += 2) {
        int i = i0 + pl;
        if (i < m) {
            int p = list[i];
            int g = gb + p;
            int bs = base[g];
            float fx = frac[g], fy = frac[PTS + g], fz = frac[2 * PTS + g];
            float w = (dxb ? fx : 1.f - fx) * (dyb ? fy : 1.f - fy) * (dzb ? fz : 1.f - fz);
            float v = vals[(size_t)g * 16 + ch];
            int yz = (bs & 1023) + dyb * 32 + dzb;
            atomicAdd(&zl[dxb][yz][ch], w * v);
        }
    }
    __syncthreads();

    size_t o0 = (size_t)bq * ZSTRF4 + ((size_t)h * 32 + x) * 4096;
    size_t o1 = (size_t)bq * ZSTRF4 + ((size_t)h * 32 + x + 1) * 4096;
    float4* bp0 = (float4*)buf0;
    float4* bp1 = (float4*)buf1;
    for (int i = tid; i < 4096; i += 256) {
        bp0[o0 + i] = zl4[i];
        bp1[o1 + i] = zl4[4096 + i];
    }
}

// ---- merge: z[p] = buf0[p] + buf1[p] (p=1..30), z[31] = buf1[31]; into buf0
__global__ __launch_bounds__(256) void k_merge(float* __restrict__ buf0,
                                               const float* __restrict__ buf1) {
    int i = blockIdx.x * 256 + threadIdx.x;
    int bq = blockIdx.y;
    int hp = i >> 12;
    int h = hp / 31, p = hp % 31 + 1;
    int q = i & 4095;
    size_t o = (size_t)bq * ZSTRF4 + (((size_t)h * 32 + p) << 12) + q;
    float4 a = ((const float4*)buf1)[o];
    if (p < 31) {
        float4 c = ((const float4*)buf0)[o];
        a.x += c.x; a.y += c.y; a.z += c.z; a.w += c.w;
    }
    ((float4*)buf0)[o] = a;
}

// ---- grouped 3x3x3 conv via bf16 MFMA: D[16fo x 16cells], K=432 pad 448 ---
// block: 2x * 8y * 32z cells; LDS tile [4][10][34][16ci] bf16 with halo
__global__ __launch_bounds__(256) void k_conv(const float* __restrict__ z,
                                              const unsigned short* __restrict__ wApack,
                                              const float* __restrict__ cb,
                                              float* __restrict__ zc) {
    __shared__ __align__(16) unsigned short zl[4][10][34][16];   // 43,520 B
    int bx = blockIdx.x;      // 0..15 -> x pair
    int yq = blockIdx.y;      // 0..3  -> 8 y rows
    int gz = blockIdx.z;      // h + 8*bq
    int h  = gz & 7;
    int bq = gz >> 3;
    int tid = threadIdx.x;
    int lane = tid & 63, wid = tid >> 6;
    int x2 = bx * 2;

    const float* zb = z + (size_t)bq * ZSTRF;
    float* zcb = zc + (size_t)bq * ZSTRF;

    // ---- load the 14 A-fragments (weights) for this head ----
    short8v af[14];
    const short8v* wa = (const short8v*)(wApack + (size_t)h * 14 * 64 * 8);
#pragma unroll
    for (int m = 0; m < 14; ++m) af[m] = wa[m * 64 + lane];

    // ---- stage z tile -> bf16 LDS (zero halo) ----
    for (int i = tid; i < 4 * 10 * 34; i += 256) {
        int dxi = i / 340, rem = i % 340;
        int yy = rem / 34, zi = rem % 34;
        int gx = x2 + dxi - 1, gy = yq * 8 + yy - 1, gzz = zi - 1;
        ushort4* d4 = (ushort4*)(&zl[0][0][0][0] + (size_t)i * 16);
        if (gx >= 0 && gx < SS && gy >= 0 && gy < SS && gzz >= 0 && gzz < SS) {
            const float4* src = (const float4*)&zb[((size_t)h * S3 +
                                 (gx * 1024 + gy * 32 + gzz)) * 16];
#pragma unroll
            for (int q = 0; q < 4; ++q) {
                float4 v = src[q];
                d4[q] = make_ushort4(f2bf(v.x), f2bf(v.y), f2bf(v.z), f2bf(v.w));
            }
        } else {
            ushort4 zz4 = make_ushort4(0, 0, 0, 0);
            d4[0] = zz4; d4[1] = zz4; d4[2] = zz4; d4[3] = zz4;
        }
    }
    __syncthreads();

    // ---- compute: each wave does 8 cell-groups of 16 cells ----
    bool lo = (lane & 32) == 0;          // taps 2m (true) vs 2m+1
    int ci0 = (lane & 16) ? 8 : 0;
    int l15 = lane & 15;
    int fo0 = (lane >> 4) * 4;
    float4 bias = *(const float4*)&cb[h * 16 + fo0];
    const unsigned short* zlf = &zl[0][0][0][0];

#pragma unroll 1
    for (int i = 0; i < 8; ++i) {
        int gi = wid * 8 + i;
        int xl = gi >> 4, yl = (gi >> 1) & 7, zz0 = (gi & 1) * 16;
        int invbase = xl * 340 + yl * 34 + zz0 + l15;

        f32x4 acc = {0.f, 0.f, 0.f, 0.f};
#pragma unroll
        for (int m = 0; m < 14; ++m) {
            const int t0 = 2 * m;
            const int t1 = (2 * m + 1 > 26) ? 26 : (2 * m + 1);
            const int off0 = (t0 / 9) * 340 + ((t0 % 9) / 3) * 34 + (t0 % 3);
            const int off1 = (t1 / 9) * 340 + ((t1 % 9) / 3) * 34 + (t1 % 3);
            int offc = lo ? off0 : off1;
            const short8v* bp = (const short8v*)(zlf + (size_t)(invbase + offc) * 16 + ci0);
            acc = __builtin_amdgcn_mfma_f32_16x16x32_bf16(af[m], *bp, acc, 0, 0, 0);
        }
        int cell = (x2 + xl) * 1024 + (yq * 8 + yl) * 32 + zz0 + l15;
        float4 o;
        o.x = acc[0] + bias.x; o.y = acc[1] + bias.y;
        o.z = acc[2] + bias.z; o.w = acc[3] + bias.w;
        *(float4*)&zcb[((size_t)h * S3 + cell) * 16 + fo0] = o;
    }
}

// --- slice: thread per (point, fo-quad); zc [bq][h][cell][16] --------------
__global__ __launch_bounds__(256) void k_slice(const int* __restrict__ base,
                                               const float* __restrict__ frac,
                                               const float* __restrict__ zc,
                                               float* __restrict__ out, int b0) {
    int lid = blockIdx.x * 256 + threadIdx.x;
    int foq = blockIdx.y;
    int bq = blockIdx.z;
    int b = b0 + bq;
    int h = lid >> 12, n = lid & 4095;
    int gid = b * BPT + lid;
    int bs = base[gid];
    float fx = frac[gid], fy = frac[PTS + gid], fz = frac[2 * PTS + gid];
    float wx[2] = {1.f - fx, fx}, wy[2] = {1.f - fy, fy}, wz[2] = {1.f - fz, fz};
    const float* zb = zc + (size_t)bq * ZSTRF + (size_t)h * S3 * FF + foq * 4;

    float a0 = 0.f, a1 = 0.f, a2 = 0.f, a3 = 0.f;
#pragma unroll
    for (int dx = 0; dx < 2; ++dx)
#pragma unroll
    for (int dy = 0; dy < 2; ++dy)
#pragma unroll
    for (int dz = 0; dz < 2; ++dz) {
        int cell = bs + dx * (SS * SS) + dy * SS + dz;
        float w = wx[dx] * wy[dy] * wz[dz];
        float4 v = *reinterpret_cast<const float4*>(&zb[(size_t)cell * FF]);
        a0 = fmaf(v.x, w, a0); a1 = fmaf(v.y, w, a1);
        a2 = fmaf(v.z, w, a2); a3 = fmaf(v.w, w, a3);
    }
    size_t ob = ((size_t)b * (HH * FF) + h * FF + foq * 4) * NP + n;
    out[ob]          = a0;
    out[ob + NP]     = a1;
    out[ob + 2 * NP] = a2;
    out[ob + 3 * NP] = a3;
}

// ------------- BN stats over (B,N) for the 128 sliced channels -------------
__global__ __launch_bounds__(256) void k_stats2(const float* __restrict__ out,
                                                const float* __restrict__ ag,
                                                const float* __restrict__ ab,
                                                float* __restrict__ A2,
                                                float* __restrict__ B2) {
    int c = blockIdx.x, tid = threadIdx.x;
    float s = 0.f, ss = 0.f;
    for (int b = 0; b < BB; ++b) {
        const float* p = out + ((size_t)b * (HH * FF) + c) * NP;
        for (int n = tid; n < NP; n += 256) { float v = p[n]; s += v; ss = fmaf(v, v, ss); }
    }
#pragma unroll
    for (int off = 32; off > 0; off >>= 1) { s += __shfl_down(s, off); ss += __shfl_down(ss, off); }
    __shared__ float sh[8];
    int lane = tid & 63, w = tid >> 6;
    if (lane == 0) { sh[w] = s; sh[4 + w] = ss; }
    __syncthreads();
    if (tid == 0) {
        float S_ = sh[0] + sh[1] + sh[2] + sh[3];
        float SSv = sh[4] + sh[5] + sh[6] + sh[7];
        float mean = S_ * (1.f / BN_CNT);
        float var  = SSv * (1.f / BN_CNT) - mean * mean;
        float rstd = rsqrtf(var + EPSV);
        A2[c] = rstd * ag[c];
        B2[c] = ab[c] - mean * rstd * ag[c];
    }
}

// ---------------- final BN + ReLU in-place on d_out ------------------------
__global__ __launch_bounds__(256) void k_bnrelu(float* __restrict__ out,
                                                const float* __restrict__ A2,
                                                const float* __restrict__ B2) {
    int gid = blockIdx.x * 256 + threadIdx.x;
    int c = (gid >> 12) & 127;
    float v = out[gid];
    out[gid] = fmaxf(fmaf(A2[c], v, B2[c]), 0.f);
}

// ---------------------------------------------------------------------------
extern "C" void kernel_launch(void* const* d_in, const int* in_sizes, int n_in,
                              void* d_out, int out_size, void* d_ws, size_t ws_size,
                              hipStream_t stream) {
    (void)in_sizes; (void)n_in; (void)out_size;
    const float* x   = (const float*)d_in[0];
    const float* pcd = (const float*)d_in[1];
    const float* W   = (const float*)d_in[2];
    const float* kg  = (const float*)d_in[3];
    const float* kb  = (const float*)d_in[4];
    const float* vg  = (const float*)d_in[5];
    const float* vb  = (const float*)d_in[6];
    const float* R   = (const float*)d_in[7];
    const float* t   = (const float*)d_in[8];
    const float* cw  = (const float*)d_in[9];
    const float* cb  = (const float*)d_in[10];
    const float* ag  = (const float*)d_in[11];
    const float* ab  = (const float*)d_in[12];
    float* out = (float*)d_out;
    char* ws = (char*)d_ws;

    // fixed workspace region (40,898,560 B)
    float* kv   = (float*)(ws + 0);            // 19,922,944; dead after k_prep
    int*   base = (int*)  (ws + 19922944ULL);  //  1,048,576
    float* frac = (float*)(ws + 20971520ULL);  //  3,145,728
    float* A    = (float*)(ws + 24117248ULL);  //  1,024
    float* Bv   = (float*)(ws + 24118272ULL);  //  1,024
    float* A2   = (float*)(ws + 24119296ULL);  //  1,024
    float* B2   = (float*)(ws + 24120320ULL);  //  1,024
    float* vals = (float*)(ws + 24121344ULL);  // 16,777,216 [point][16]
    // wApack lives in the tail of the (dead-after-prep) kv region:
    // bytes 16,777,216 .. 16,891,904  (114,688 B) — written AFTER k_prep.
    unsigned short* wApack = (unsigned short*)(ws + 16777216ULL);

    int NB = 1;
    if (ws_size >= 40898560ULL + 4ULL * 33554432ULL)      NB = 4;  // 175,116,288
    else if (ws_size >= 40898560ULL + 2ULL * 33554432ULL) NB = 2;  // 108,007,424

    float *buf0, *buf1;
    if (NB == 1) {
        buf0 = kv;                              // bytes 0..16,777,216 (no overlap w/ wApack)
        buf1 = (float*)(ws + 40898560ULL);
    } else {
        buf0 = (float*)(ws + 40898560ULL);
        buf1 = buf0 + (size_t)NB * ZSTRF;
    }

    k_gemm<<<dim3(10, 16, BB), 256, 0, stream>>>(x, W, kv);
    k_stats_kv<<<dim3(CC), 256, 0, stream>>>(kv, kg, kb, vg, vb, A, Bv);
    k_prep<<<dim3(PTS / 256), 256, 0, stream>>>(kv, pcd, A, Bv, R, t, base, frac, vals);
    k_wpack<<<dim3(28), 256, 0, stream>>>(cw, wApack);   // after prep: kv region free

    for (int b0 = 0; b0 < BB; b0 += NB) {
        k_splat<<<dim3(31, 8, NB), 256, 0, stream>>>(base, frac, vals, buf0, buf1, b0);
        k_merge<<<dim3(3968, NB), 256, 0, stream>>>(buf0, buf1);
        k_conv<<<dim3(16, 4, HH * NB), 256, 0, stream>>>(buf0, wApack, cb, buf1);
        k_slice<<<dim3(BPT / 256, 4, NB), 256, 0, stream>>>(base, frac, buf1, out, b0);
    }

    k_stats2<<<dim3(HH * FF), 256, 0, stream>>>(out, ag, ab, A2, B2);
    k_bnrelu<<<dim3((BB * HH * FF * NP) / 256), 256, 0, stream>>>(out, A2, B2);
}

// Round 7
// 635.866 us; speedup vs baseline: 5.0419x; 1.3274x over previous
//
#include <hip/hip_runtime.h>
#include <cstddef>
#include <cstdint>

#define BB 8
#define MD 256
#define NP 4096
#define HH 8
#define FF 16
#define SS 32
#define S3 32768
#define CC 152      // H*(F+3)
#define KC 24       // H*3
#define PTS (BB*HH*NP)   // 262144
#define BPT (HH*NP)      // points per batch = 32768
#define BN_CNT (BB*NP)   // 32768
#define EPSV 1e-5f
#define ZSTRF (HH*S3*FF)     // per-batch lattice floats = 4,194,304
#define ZSTRF4 (ZSTRF/4)     // in float4 units

typedef __attribute__((ext_vector_type(8))) short short8v;
typedef __attribute__((ext_vector_type(4))) float f32x4;

__device__ __forceinline__ unsigned short f2bf(float f) {
    unsigned int u = __float_as_uint(f);
    unsigned int r = u + 0x7FFFu + ((u >> 16) & 1u);   // round-to-nearest-even
    return (unsigned short)(r >> 16);
}

// -------- GEMM: kv[b,o,n] = sum_m W[o,m] * x[b,m,n]; 16 oc per block -------
__global__ __launch_bounds__(256) void k_gemm(const float* __restrict__ x,
                                              const float* __restrict__ W,
                                              float* __restrict__ kv) {
    int oc0 = blockIdx.x * 16;
    int nt  = blockIdx.y;
    int b   = blockIdx.z;
    int tid = threadIdx.x;
    int n = nt * 256 + tid;

    float acc[16];
#pragma unroll
    for (int r = 0; r < 16; ++r) acc[r] = 0.f;
    const float* xb = x + (size_t)b * MD * NP + n;
#pragma unroll 4
    for (int m = 0; m < MD; ++m) {
        float xv = xb[(size_t)m * NP];
#pragma unroll
        for (int r = 0; r < 16; ++r) {
            int rr = (oc0 + r < CC) ? (oc0 + r) : (CC - 1);
            acc[r] = fmaf(W[(size_t)rr * MD + m], xv, acc[r]);
        }
    }
#pragma unroll
    for (int r = 0; r < 16; ++r)
        if (oc0 + r < CC)
            kv[((size_t)b * CC + oc0 + r) * NP + n] = acc[r];
}

// ------------- BN stats over (B,N) for all 152 kv channels -----------------
__global__ __launch_bounds__(256) void k_stats_kv(const float* __restrict__ kv,
                                                  const float* __restrict__ kg,
                                                  const float* __restrict__ kb,
                                                  const float* __restrict__ vg,
                                                  const float* __restrict__ vb,
                                                  float* __restrict__ A,
                                                  float* __restrict__ Bv) {
    int o = blockIdx.x, tid = threadIdx.x;
    float s = 0.f, ss = 0.f;
    for (int b = 0; b < BB; ++b) {
        const float* p = kv + ((size_t)b * CC + o) * NP;
        for (int n = tid; n < NP; n += 256) { float v = p[n]; s += v; ss = fmaf(v, v, ss); }
    }
#pragma unroll
    for (int off = 32; off > 0; off >>= 1) { s += __shfl_down(s, off); ss += __shfl_down(ss, off); }
    __shared__ float sh[8];
    int lane = tid & 63, w = tid >> 6;
    if (lane == 0) { sh[w] = s; sh[4 + w] = ss; }
    __syncthreads();
    if (tid == 0) {
        float S_ = sh[0] + sh[1] + sh[2] + sh[3];
        float SSv = sh[4] + sh[5] + sh[6] + sh[7];
        float mean = S_ * (1.f / BN_CNT);
        float var  = SSv * (1.f / BN_CNT) - mean * mean;
        float rstd = rsqrtf(var + EPSV);
        float g  = (o < KC) ? kg[o] : vg[o - KC];
        float be = (o < KC) ? kb[o] : vb[o - KC];
        A[o]  = rstd * g;
        Bv[o] = be - mean * rstd * g;
    }
}

// --- per-point: BN keys -> affine -> tanh -> idx/frac; also emit vals[.,16] -
__global__ __launch_bounds__(256) void k_prep(const float* __restrict__ kv,
                                              const float* __restrict__ pcd,
                                              const float* __restrict__ A,
                                              const float* __restrict__ Bv,
                                              const float* __restrict__ R,
                                              const float* __restrict__ t,
                                              int* __restrict__ base,
                                              float* __restrict__ frac,
                                              float* __restrict__ vals) {
    int gid = blockIdx.x * 256 + threadIdx.x;
    int b = gid >> 15, h = (gid >> 12) & 7, n = gid & 4095;

    float p[3];
#pragma unroll
    for (int i = 0; i < 3; ++i) {
        int c = h * 3 + i;
        float v = kv[((size_t)b * CC + c) * NP + n];
        p[i] = pcd[((size_t)b * 3 + i) * NP + n] + fmaf(A[c], v, Bv[c]);
    }
    int fl[3]; float fr[3];
#pragma unroll
    for (int i = 0; i < 3; ++i) {
        float key = R[h * 9 + i * 3 + 0] * p[0] + R[h * 9 + i * 3 + 1] * p[1] +
                    R[h * 9 + i * 3 + 2] * p[2] + t[h * 3 + i];
        float lat = tanhf(key);
        float pos = (lat + 1.f) * 0.5f * (SS - 1);
        float flf = fminf(fmaxf(floorf(pos), 0.f), (float)(SS - 2));
        fr[i] = pos - flf;
        fl[i] = (int)flf;
    }
    base[gid] = (fl[0] * SS + fl[1]) * SS + fl[2];
    frac[gid]           = fr[0];
    frac[PTS + gid]     = fr[1];
    frac[2 * PTS + gid] = fr[2];

    float4* vo = (float4*)(vals + (size_t)gid * 16);
#pragma unroll
    for (int q = 0; q < 4; ++q) {
        float4 v;
        float* vv = (float*)&v;
#pragma unroll
        for (int j = 0; j < 4; ++j) {
            int c = KC + h * FF + q * 4 + j;
            vv[j] = fmaf(A[c], kv[((size_t)b * CC + c) * NP + n], Bv[c]);
        }
        vo[q] = v;
    }
}

// ---- pack conv weights into MFMA A-fragment lane order (bf16) -------------
__global__ __launch_bounds__(256) void k_wpack(const float* __restrict__ cw,
                                               unsigned short* __restrict__ wApack) {
    int gid = blockIdx.x * 256 + threadIdx.x;     // (h*14 + m)*64 + lane
    if (gid >= 8 * 14 * 64) return;
    int lane = gid & 63;
    int m = (gid >> 6) % 14;
    int h = gid / (14 * 64);
    int fo = lane & 15, g = lane >> 4;
    int tap = 2 * m + (g >> 1);
    int ci0 = (g & 1) * 8;
    unsigned short o[8];
#pragma unroll
    for (int j = 0; j < 8; ++j) {
        float w = (tap <= 26) ? cw[((size_t)(h * 16 + fo) * 16 + ci0 + j) * 27 + tap] : 0.f;
        o[j] = f2bf(w);
    }
    ushort4* dst = (ushort4*)(wApack + (size_t)gid * 8);
    dst[0] = make_ushort4(o[0], o[1], o[2], o[3]);
    dst[1] = make_ushort4(o[4], o[5], o[6], o[7]);
}

// --- splat: block per OUTPUT plane (x, h, bq); LDS 1-plane accumulation ----
// plane x receives: slab x (dx=0 corners) + slab x-1 (dx=1 corners)
__global__ __launch_bounds__(512) void k_splat(const int* __restrict__ base,
                                               const float* __restrict__ frac,
                                               const float* __restrict__ vals,
                                               float* __restrict__ zout, int b0) {
    __shared__ float zl[1024][16];           // 64 KB, fp32 accumulate
    __shared__ unsigned short list[4096];    // 8 KB
    __shared__ int cnt;
    int x = blockIdx.x;    // 0..31 output plane
    int h = blockIdx.y;
    int bq = blockIdx.z;
    int b = b0 + bq;
    int tid = threadIdx.x;

    float4 zero4 = make_float4(0.f, 0.f, 0.f, 0.f);
    float4* zl4 = (float4*)zl;
    for (int i = tid; i < 4096; i += 512) zl4[i] = zero4;
    if (tid == 0) cnt = 0;
    __syncthreads();

    int gb = b * BPT + h * NP;
    for (int p = tid; p < NP; p += 512) {
        int s = base[gb + p] >> 10;
        if (s == x || s + 1 == x) { int i = atomicAdd(&cnt, 1); list[i] = (unsigned short)p; }
    }
    __syncthreads();
    int m = cnt;

    int pl  = tid >> 6;          // 8 points per pass
    int idx = tid & 63;
    int cor = idx >> 4;          // 0..3 -> (dy, dz)
    int ch  = idx & 15;
    int dyb = cor >> 1, dzb = cor & 1;
    for (int i0 = 0; i0 < m; i0 += 8) {
        int i = i0 + pl;
        if (i < m) {
            int p = list[i];
            int g = gb + p;
            int bs = base[g];
            int dxb = x - (bs >> 10);     // 0 or 1
            float fx = frac[g], fy = frac[PTS + g], fz = frac[2 * PTS + g];
            float w = (dxb ? fx : 1.f - fx) * (dyb ? fy : 1.f - fy) * (dzb ? fz : 1.f - fz);
            float v = vals[(size_t)g * 16 + ch];
            int yz = (bs & 1023) + dyb * 32 + dzb;
            atomicAdd(&zl[yz][ch], w * v);
        }
    }
    __syncthreads();

    // write the finished plane: z[bq][h][x*1024 .. +1024][16]
    size_t o = (size_t)bq * ZSTRF4 + ((size_t)h * 32 + x) * 4096;
    float4* zo = (float4*)zout;
    for (int i = tid; i < 4096; i += 512) zo[o + i] = zl4[i];
}

// ---- grouped 3x3x3 conv via bf16 MFMA: D[16fo x 16cells], K=432 pad 448 ---
__global__ __launch_bounds__(256) void k_conv(const float* __restrict__ z,
                                              const unsigned short* __restrict__ wApack,
                                              const float* __restrict__ cb,
                                              float* __restrict__ zc) {
    __shared__ __align__(16) unsigned short zl[4][10][34][16];   // 43,520 B
    int bx = blockIdx.x;      // 0..15 -> x pair
    int yq = blockIdx.y;      // 0..3  -> 8 y rows
    int gz = blockIdx.z;      // h + 8*bq
    int h  = gz & 7;
    int bq = gz >> 3;
    int tid = threadIdx.x;
    int lane = tid & 63, wid = tid >> 6;
    int x2 = bx * 2;

    const float* zb = z + (size_t)bq * ZSTRF;
    float* zcb = zc + (size_t)bq * ZSTRF;

    short8v af[14];
    const short8v* wa = (const short8v*)(wApack + (size_t)h * 14 * 64 * 8);
#pragma unroll
    for (int m = 0; m < 14; ++m) af[m] = wa[m * 64 + lane];

    for (int i = tid; i < 4 * 10 * 34; i += 256) {
        int dxi = i / 340, rem = i % 340;
        int yy = rem / 34, zi = rem % 34;
        int gx = x2 + dxi - 1, gy = yq * 8 + yy - 1, gzz = zi - 1;
        ushort4* d4 = (ushort4*)(&zl[0][0][0][0] + (size_t)i * 16);
        if (gx >= 0 && gx < SS && gy >= 0 && gy < SS && gzz >= 0 && gzz < SS) {
            const float4* src = (const float4*)&zb[((size_t)h * S3 +
                                 (gx * 1024 + gy * 32 + gzz)) * 16];
#pragma unroll
            for (int q = 0; q < 4; ++q) {
                float4 v = src[q];
                d4[q] = make_ushort4(f2bf(v.x), f2bf(v.y), f2bf(v.z), f2bf(v.w));
            }
        } else {
            ushort4 zz4 = make_ushort4(0, 0, 0, 0);
            d4[0] = zz4; d4[1] = zz4; d4[2] = zz4; d4[3] = zz4;
        }
    }
    __syncthreads();

    bool lo = (lane & 32) == 0;
    int ci0 = (lane & 16) ? 8 : 0;
    int l15 = lane & 15;
    int fo0 = (lane >> 4) * 4;
    float4 bias = *(const float4*)&cb[h * 16 + fo0];
    const unsigned short* zlf = &zl[0][0][0][0];

#pragma unroll 1
    for (int i = 0; i < 8; ++i) {
        int gi = wid * 8 + i;
        int xl = gi >> 4, yl = (gi >> 1) & 7, zz0 = (gi & 1) * 16;
        int invbase = xl * 340 + yl * 34 + zz0 + l15;

        f32x4 acc = {0.f, 0.f, 0.f, 0.f};
#pragma unroll
        for (int m = 0; m < 14; ++m) {
            const int t0 = 2 * m;
            const int t1 = (2 * m + 1 > 26) ? 26 : (2 * m + 1);
            const int off0 = (t0 / 9) * 340 + ((t0 % 9) / 3) * 34 + (t0 % 3);
            const int off1 = (t1 / 9) * 340 + ((t1 % 9) / 3) * 34 + (t1 % 3);
            int offc = lo ? off0 : off1;
            const short8v* bp = (const short8v*)(zlf + (size_t)(invbase + offc) * 16 + ci0);
            acc = __builtin_amdgcn_mfma_f32_16x16x32_bf16(af[m], *bp, acc, 0, 0, 0);
        }
        int cell = (x2 + xl) * 1024 + (yq * 8 + yl) * 32 + zz0 + l15;
        float4 o;
        o.x = acc[0] + bias.x; o.y = acc[1] + bias.y;
        o.z = acc[2] + bias.z; o.w = acc[3] + bias.w;
        *(float4*)&zcb[((size_t)h * S3 + cell) * 16 + fo0] = o;
    }
}

// --- slice: thread per (point, fo-quad); zc [bq][h][cell][16] --------------
__global__ __launch_bounds__(256) void k_slice(const int* __restrict__ base,
                                               const float* __restrict__ frac,
                                               const float* __restrict__ zc,
                                               float* __restrict__ out, int b0) {
    int lid = blockIdx.x * 256 + threadIdx.x;
    int foq = blockIdx.y;
    int bq = blockIdx.z;
    int b = b0 + bq;
    int h = lid >> 12, n = lid & 4095;
    int gid = b * BPT + lid;
    int bs = base[gid];
    float fx = frac[gid], fy = frac[PTS + gid], fz = frac[2 * PTS + gid];
    float wx[2] = {1.f - fx, fx}, wy[2] = {1.f - fy, fy}, wz[2] = {1.f - fz, fz};
    const float* zb = zc + (size_t)bq * ZSTRF + (size_t)h * S3 * FF + foq * 4;

    float a0 = 0.f, a1 = 0.f, a2 = 0.f, a3 = 0.f;
#pragma unroll
    for (int dx = 0; dx < 2; ++dx)
#pragma unroll
    for (int dy = 0; dy < 2; ++dy)
#pragma unroll
    for (int dz = 0; dz < 2; ++dz) {
        int cell = bs + dx * (SS * SS) + dy * SS + dz;
        float w = wx[dx] * wy[dy] * wz[dz];
        float4 v = *reinterpret_cast<const float4*>(&zb[(size_t)cell * FF]);
        a0 = fmaf(v.x, w, a0); a1 = fmaf(v.y, w, a1);
        a2 = fmaf(v.z, w, a2); a3 = fmaf(v.w, w, a3);
    }
    size_t ob = ((size_t)b * (HH * FF) + h * FF + foq * 4) * NP + n;
    out[ob]          = a0;
    out[ob + NP]     = a1;
    out[ob + 2 * NP] = a2;
    out[ob + 3 * NP] = a3;
}

// ------------- BN stats over (B,N) for the 128 sliced channels -------------
__global__ __launch_bounds__(256) void k_stats2(const float* __restrict__ out,
                                                const float* __restrict__ ag,
                                                const float* __restrict__ ab,
                                                float* __restrict__ A2,
                                                float* __restrict__ B2) {
    int c = blockIdx.x, tid = threadIdx.x;
    float s = 0.f, ss = 0.f;
    for (int b = 0; b < BB; ++b) {
        const float* p = out + ((size_t)b * (HH * FF) + c) * NP;
        for (int n = tid; n < NP; n += 256) { float v = p[n]; s += v; ss = fmaf(v, v, ss); }
    }
#pragma unroll
    for (int off = 32; off > 0; off >>= 1) { s += __shfl_down(s, off); ss += __shfl_down(ss, off); }
    __shared__ float sh[8];
    int lane = tid & 63, w = tid >> 6;
    if (lane == 0) { sh[w] = s; sh[4 + w] = ss; }
    __syncthreads();
    if (tid == 0) {
        float S_ = sh[0] + sh[1] + sh[2] + sh[3];
        float SSv = sh[4] + sh[5] + sh[6] + sh[7];
        float mean = S_ * (1.f / BN_CNT);
        float var  = SSv * (1.f / BN_CNT) - mean * mean;
        float rstd = rsqrtf(var + EPSV);
        A2[c] = rstd * ag[c];
        B2[c] = ab[c] - mean * rstd * ag[c];
    }
}

// ---------------- final BN + ReLU in-place on d_out ------------------------
__global__ __launch_bounds__(256) void k_bnrelu(float* __restrict__ out,
                                                const float* __restrict__ A2,
                                                const float* __restrict__ B2) {
    int gid = blockIdx.x * 256 + threadIdx.x;
    int c = (gid >> 12) & 127;
    float v = out[gid];
    out[gid] = fmaxf(fmaf(A2[c], v, B2[c]), 0.f);
}

// ---------------------------------------------------------------------------
extern "C" void kernel_launch(void* const* d_in, const int* in_sizes, int n_in,
                              void* d_out, int out_size, void* d_ws, size_t ws_size,
                              hipStream_t stream) {
    (void)in_sizes; (void)n_in; (void)out_size;
    const float* x   = (const float*)d_in[0];
    const float* pcd = (const float*)d_in[1];
    const float* W   = (const float*)d_in[2];
    const float* kg  = (const float*)d_in[3];
    const float* kb  = (const float*)d_in[4];
    const float* vg  = (const float*)d_in[5];
    const float* vb  = (const float*)d_in[6];
    const float* R   = (const float*)d_in[7];
    const float* t   = (const float*)d_in[8];
    const float* cw  = (const float*)d_in[9];
    const float* cb  = (const float*)d_in[10];
    const float* ag  = (const float*)d_in[11];
    const float* ab  = (const float*)d_in[12];
    float* out = (float*)d_out;
    char* ws = (char*)d_ws;

    // fixed workspace region (40,898,560 B)
    float* kv   = (float*)(ws + 0);            // 19,922,944; dead after k_prep
    int*   base = (int*)  (ws + 19922944ULL);  //  1,048,576
    float* frac = (float*)(ws + 20971520ULL);  //  3,145,728
    float* A    = (float*)(ws + 24117248ULL);  //  1,024
    float* Bv   = (float*)(ws + 24118272ULL);  //  1,024
    float* A2   = (float*)(ws + 24119296ULL);  //  1,024
    float* B2   = (float*)(ws + 24120320ULL);  //  1,024
    float* vals = (float*)(ws + 24121344ULL);  // 16,777,216 [point][16]
    // wApack in the tail of the dead-after-prep kv region
    unsigned short* wApack = (unsigned short*)(ws + 16777216ULL);

    int NB = 1;
    if (ws_size >= 40898560ULL + 4ULL * 33554432ULL)      NB = 4;  // 175,116,288
    else if (ws_size >= 40898560ULL + 2ULL * 33554432ULL) NB = 2;  // 108,007,424

    float *buf0, *buf1;
    if (NB == 1) {
        buf0 = kv;                              // no overlap with wApack tail
        buf1 = (float*)(ws + 40898560ULL);
    } else {
        buf0 = (float*)(ws + 40898560ULL);
        buf1 = buf0 + (size_t)NB * ZSTRF;
    }

    k_gemm<<<dim3(10, 16, BB), 256, 0, stream>>>(x, W, kv);
    k_stats_kv<<<dim3(CC), 256, 0, stream>>>(kv, kg, kb, vg, vb, A, Bv);
    k_prep<<<dim3(PTS / 256), 256, 0, stream>>>(kv, pcd, A, Bv, R, t, base, frac, vals);
    k_wpack<<<dim3(28), 256, 0, stream>>>(cw, wApack);

    for (int b0 = 0; b0 < BB; b0 += NB) {
        k_splat<<<dim3(SS, 8, NB), 512, 0, stream>>>(base, frac, vals, buf0, b0);
        k_conv<<<dim3(16, 4, HH * NB), 256, 0, stream>>>(buf0, wApack, cb, buf1);
        k_slice<<<dim3(BPT / 256, 4, NB), 256, 0, stream>>>(base, frac, buf1, out, b0);
    }

    k_stats2<<<dim3(HH * FF), 256, 0, stream>>>(out, ag, ab, A2, B2);
    k_bnrelu<<<dim3((BB * HH * FF * NP) / 256), 256, 0, stream>>>(out, A2, B2);
}